// Round 5
// baseline (15650.046 us; speedup 1.0000x reference)
//
#include <hip/hip_runtime.h>
#include <hip/hip_bf16.h>
#include <math.h>

constexpr int SEQ    = 2048;
constexpr int NH     = 16;
constexpr int HEAVY  = 204;   // int(0.1*2048)
constexpr int RECENT = 204;   // int(0.1*2048)
constexpr float SCALE = 0.08838834764831845f; // 128^-0.5

__device__ __forceinline__ float blockReduceMax128(float v, float* red, int t) {
  red[t] = v; __syncthreads();
  for (int s = 64; s > 0; s >>= 1) {
    if (t < s) red[t] = fmaxf(red[t], red[t + s]);
    __syncthreads();
  }
  float r = red[0]; __syncthreads();
  return r;
}
__device__ __forceinline__ float blockReduceSum128(float v, float* red, int t) {
  red[t] = v; __syncthreads();
  for (int s = 64; s > 0; s >>= 1) {
    if (t < s) red[t] = red[t] + red[t + s];
    __syncthreads();
  }
  float r = red[0]; __syncthreads();
  return r;
}

// ---------- naive GEMM: C[m][n] = sum_k A[m][k]*B[k][n] + bias[n] ----------
__global__ void gemm_simple(const float* __restrict__ A,
                            const float* __restrict__ B,
                            const float* __restrict__ bias,
                            float* __restrict__ C, int M, int N, int K) {
  int n = blockIdx.x * 16 + threadIdx.x;
  int m = blockIdx.y * 16 + threadIdx.y;
  if (m >= M || n >= N) return;
  float acc = 0.f;
  for (int k = 0; k < K; ++k)
    acc += A[(size_t)m * K + k] * B[(size_t)k * N + n];
  if (bias) acc += bias[n];
  C[(size_t)m * N + n] = acc;
}

// ---------- in-place RoPE on x[s][h*128+d], H heads ----------
__global__ void rope_simple(float* __restrict__ x, const float* __restrict__ cosb,
                            const float* __restrict__ sinb, int H) {
  int idx = blockIdx.x * 256 + threadIdx.x;
  int total = SEQ * H * 64;
  if (idx >= total) return;
  int d = idx & 63;
  int rest = idx >> 6;
  int h = rest % H;
  int s = rest / H;
  float* p = x + (size_t)s * (H * 128) + h * 128;
  float x1 = p[d], x2 = p[d + 64];
  float c1 = cosb[(size_t)s * 128 + d];
  float c2 = cosb[(size_t)s * 128 + d + 64];
  float s1 = sinb[(size_t)s * 128 + d];
  float s2 = sinb[(size_t)s * 128 + d + 64];
  p[d]      = x1 * c1 - x2 * s1;
  p[d + 64] = x2 * c2 + x1 * s2;
}

// ---------- per-(h,i) causal row softmax stats ----------
__global__ __launch_bounds__(128) void rowstats2(
    const float* __restrict__ q, const float* __restrict__ k,
    float* __restrict__ rowm, float* __restrict__ rowl) {
  int i = blockIdx.x, h = blockIdx.y, t = threadIdx.x;
  int kvh = h >> 2;
  __shared__ float qv[128];
  __shared__ float sarr[SEQ];
  __shared__ float red[128];
  qv[t] = q[(size_t)i * 2048 + h * 128 + t];
  __syncthreads();
  float lm = -INFINITY;
  for (int j = t; j <= i; j += 128) {
    const float* kp = k + (size_t)j * 512 + kvh * 128;
    float dot = 0.f;
    for (int d = 0; d < 128; ++d) dot += qv[d] * kp[d];
    float sv = dot * SCALE;
    sarr[j] = sv;
    lm = fmaxf(lm, sv);
  }
  float mm = blockReduceMax128(lm, red, t);
  float ls = 0.f;
  for (int j = t; j <= i; j += 128) ls += expf(sarr[j] - mm);
  float ll = blockReduceSum128(ls, red, t);
  if (t == 0) { rowm[h * SEQ + i] = mm; rowl[h * SEQ + i] = ll; }
}

// ---------- colsum[h][j] = sum_i softmax(scores)[i][j] (f64 accumulate) ----------
__global__ __launch_bounds__(128) void colsum2(
    const float* __restrict__ q, const float* __restrict__ k,
    const float* __restrict__ rowm, const float* __restrict__ rowl,
    float* __restrict__ colsum) {
  int j = blockIdx.x, h = blockIdx.y, t = threadIdx.x;
  int kvh = h >> 2;
  __shared__ float kv[128];
  __shared__ double redd[128];
  kv[t] = k[(size_t)j * 512 + kvh * 128 + t];
  __syncthreads();
  double ps = 0.0;
  for (int i = j + t; i < SEQ; i += 128) {
    const float* qp = q + (size_t)i * 2048 + h * 128;
    float dot = 0.f;
    for (int d = 0; d < 128; ++d) dot += kv[d] * qp[d];
    ps += (double)(expf(dot * SCALE - rowm[h * SEQ + i]) / rowl[h * SEQ + i]);
  }
  redd[t] = ps; __syncthreads();
  for (int s = 64; s > 0; s >>= 1) {
    if (t < s) redd[t] += redd[t + s];
    __syncthreads();
  }
  if (t == 0) colsum[h * SEQ + j] = (float)redd[0];
}

// ---------- top-HEAVY per head (iterative argmax, lowest-index ties) ----------
__global__ __launch_bounds__(64) void topk_k(const float* __restrict__ colsum,
                                             int* __restrict__ hidx) {
  int h = blockIdx.x, t = threadIdx.x;
  __shared__ float vals[SEQ];
  for (int j = t; j < SEQ; j += 64) vals[j] = colsum[h * SEQ + j];
  __syncthreads();
  for (int it = 0; it < HEAVY; ++it) {
    float bv = -INFINITY; int bi = SEQ - 1;
    for (int j = t; j < SEQ; j += 64) {
      float v = vals[j];
      if (v > bv) { bv = v; bi = j; }
    }
    for (int off = 32; off > 0; off >>= 1) {
      float ov = __shfl_xor(bv, off, 64);
      int   oi = __shfl_xor(bi, off, 64);
      if (ov > bv || (ov == bv && oi < bi)) { bv = ov; bi = oi; }
    }
    bi = min(max(bi, 0), SEQ - 1);
    if (t == 0) hidx[h * HEAVY + it] = bi;
    __syncthreads();
    vals[bi] = -INFINITY;
    __syncthreads();
  }
}

// ---------- sparse attention over heavy ∪ recent band, online softmax ----------
__global__ __launch_bounds__(128) void attn2(
    const float* __restrict__ q, const float* __restrict__ k,
    const float* __restrict__ v, const int* __restrict__ hidx,
    float* __restrict__ ctx) {
  int i = blockIdx.x, h = blockIdx.y, t = threadIdx.x;
  int kvh = h >> 2;
  __shared__ float qv[128];
  __shared__ float sp[128];
  __shared__ int jarr[128];
  __shared__ float red[128];
  qv[t] = q[(size_t)i * 2048 + h * 128 + t];
  __syncthreads();

  float m = -INFINITY, l = 0.f, acc = 0.f;
  int jb0 = max(0, i - RECENT);
  int nbc = (i - jb0 + 1 + 127) >> 7;
  int total = 2 + nbc;  // 2 heavy chunks (HEAVY=204) + band chunks

  for (int c = 0; c < total; ++c) {
    int j = 0; bool use = false;
    if (c < 2) {
      int idx = c * 128 + t;
      if (idx < HEAVY) {
        int jj = hidx[h * HEAVY + idx];
        if (jj < jb0) { j = jj; use = true; }  // band covers [jb0,i]; j>i has zero weight
      }
    } else {
      int jj = jb0 + (c - 2) * 128 + t;
      if (jj <= i) { j = jj; use = true; }
    }
    float s = -INFINITY;
    if (use) {
      const float* kp = k + (size_t)j * 512 + kvh * 128;
      float dot = 0.f;
      for (int d = 0; d < 128; ++d) dot += qv[d] * kp[d];
      s = dot * SCALE;
    }
    float cm = blockReduceMax128(s, red, t);
    if (cm == -INFINITY) continue;   // uniform across block
    float nm = fmaxf(m, cm);
    float alpha = (m == -INFINITY) ? 0.f : expf(m - nm);
    float p = use ? expf(s - nm) : 0.f;
    sp[t] = p; jarr[t] = use ? j : 0;
    float csum = blockReduceSum128(p, red, t);  // internal syncs publish sp/jarr
    l = l * alpha + csum;
    m = nm;
    acc *= alpha;
    const float* vb = v + (size_t)kvh * 128 + t;
    for (int jj2 = 0; jj2 < 128; ++jj2) {
      float pj = sp[jj2];
      if (pj > 0.f) acc += pj * vb[(size_t)jarr[jj2] * 512];
    }
    __syncthreads();
  }
  ctx[(size_t)i * 2048 + h * 128 + t] = acc / l;
}

// ---------- launch ----------
extern "C" void kernel_launch(void* const* d_in, const int* in_sizes, int n_in,
                              void* d_out, int out_size, void* d_ws, size_t ws_size,
                              hipStream_t stream) {
  const float* hs   = (const float*)d_in[0];
  const float* cosb = (const float*)d_in[1];
  const float* sinb = (const float*)d_in[2];
  // d_in[3] = attention_mask (pure causal) -- implemented analytically
  const float* Wq = (const float*)d_in[4];
  const float* bq = (const float*)d_in[5];
  const float* Wk = (const float*)d_in[6];
  const float* bk = (const float*)d_in[7];
  const float* Wv = (const float*)d_in[8];
  const float* bv = (const float*)d_in[9];
  const float* Wo = (const float*)d_in[10];
  float* out = (float*)d_out;   // reference output dtype is float32

  char* ws = (char*)d_ws;
  float* q    = (float*)ws;                     // [2048][2048] 16 MB
  float* kbuf = q + (size_t)SEQ * 2048;         // [2048][512]   4 MB
  float* vbuf = kbuf + (size_t)SEQ * 512;       // [2048][512]   4 MB
  float* ctx  = vbuf + (size_t)SEQ * 512;       // [2048][2048] 16 MB
  float* rowm = ctx + (size_t)SEQ * 2048;       // [16][2048]
  float* rowl = rowm + NH * SEQ;
  float* colsum = rowl + NH * SEQ;
  int*   hidx   = (int*)(colsum + NH * SEQ);    // [16][204]
  // total ~40.7 MB

  dim3 blk(16, 16);
  // projections (natural layouts)
  gemm_simple<<<dim3(128, 128), blk, 0, stream>>>(hs, Wq, bq, q,    SEQ, 2048, 2048);
  gemm_simple<<<dim3(32, 128),  blk, 0, stream>>>(hs, Wk, bk, kbuf, SEQ, 512,  2048);
  gemm_simple<<<dim3(32, 128),  blk, 0, stream>>>(hs, Wv, bv, vbuf, SEQ, 512,  2048);

  // RoPE in place
  rope_simple<<<(SEQ * 16 * 64 + 255) / 256, 256, 0, stream>>>(q,    cosb, sinb, 16);
  rope_simple<<<(SEQ * 4 * 64 + 255) / 256, 256, 0, stream>>>(kbuf, cosb, sinb, 4);

  // softmax row stats, column sums, top-k, sparse attention
  rowstats2<<<dim3(SEQ, NH), 128, 0, stream>>>(q, kbuf, rowm, rowl);
  colsum2<<<dim3(SEQ, NH), 128, 0, stream>>>(q, kbuf, rowm, rowl, colsum);
  topk_k<<<NH, 64, 0, stream>>>(colsum, hidx);
  attn2<<<dim3(SEQ, NH), 128, 0, stream>>>(q, kbuf, vbuf, hidx, ctx);

  // output projection -> f32 out
  gemm_simple<<<dim3(128, 128), blk, 0, stream>>>(ctx, Wo, (const float*)nullptr,
                                                  out, SEQ, 2048, 2048);
}

// Round 6
// 5893.989 us; speedup vs baseline: 2.6553x; 2.6553x over previous
//
#include <hip/hip_runtime.h>
#include <hip/hip_bf16.h>
#include <math.h>

constexpr int SEQ    = 2048;
constexpr int NH     = 16;
constexpr int HEAVY  = 204;   // int(0.1*2048)
constexpr int RECENT = 204;   // int(0.1*2048)
constexpr float SCALE = 0.08838834764831845f; // 128^-0.5

typedef _Float16 half8 __attribute__((ext_vector_type(8)));
typedef float f32x4 __attribute__((ext_vector_type(4)));

__device__ __forceinline__ float blockReduceMax128(float v, float* red, int t) {
  red[t] = v; __syncthreads();
  for (int s = 64; s > 0; s >>= 1) {
    if (t < s) red[t] = fmaxf(red[t], red[t + s]);
    __syncthreads();
  }
  float r = red[0]; __syncthreads();
  return r;
}
__device__ __forceinline__ float blockReduceSum128(float v, float* red, int t) {
  red[t] = v; __syncthreads();
  for (int s = 64; s > 0; s >>= 1) {
    if (t < s) red[t] = red[t] + red[t + s];
    __syncthreads();
  }
  float r = red[0]; __syncthreads();
  return r;
}

// ---------- f32 -> f16 convert ----------
__global__ void cvt_h(const float* __restrict__ src, _Float16* __restrict__ dst, int n) {
  int i = (blockIdx.x * 256 + threadIdx.x) * 4;
  if (i + 3 < n) {
    float4 v = *(const float4*)(src + i);
    dst[i] = (_Float16)v.x; dst[i+1] = (_Float16)v.y;
    dst[i+2] = (_Float16)v.z; dst[i+3] = (_Float16)v.w;
  } else {
    for (int u = i; u < n; ++u) dst[u] = (_Float16)src[u];
  }
}

// ---------- transpose + convert: W f32 [K][N] -> WT f16 [N][K] ----------
__global__ __launch_bounds__(256) void transpose_h(
    const float* __restrict__ W, _Float16* __restrict__ WT, int K, int N) {
  __shared__ float T[64][65];
  int c = threadIdx.x & 63, rq = threadIdx.x >> 6;
  int n0 = blockIdx.x * 64, k0 = blockIdx.y * 64;
#pragma unroll
  for (int u = 0; u < 16; ++u) {
    int r = rq * 16 + u;
    T[r][c] = W[(size_t)(k0 + r) * N + n0 + c];
  }
  __syncthreads();
#pragma unroll
  for (int u = 0; u < 16; ++u) {
    int r = rq * 16 + u;
    WT[(size_t)(n0 + r) * K + k0 + c] = (_Float16)T[c][r];
  }
}

// ---------- MFMA f16 GEMM: C[m][n] = sum_k A[m][k]*BT[n][k] + bias[n] ----------
// 128x128 tile, BK=32, 256 thr = 4 waves in 2x2, each wave 64x64 (4x4 MFMA 16x16x32).
__global__ __launch_bounds__(256) void gemm_h(
    const _Float16* __restrict__ A, const _Float16* __restrict__ BT,
    const float* __restrict__ bias, float* __restrict__ C,
    int M, int N, int K)
{
  __shared__ _Float16 As[128][40];  // +8 pad: frag b128 reads land 2-way max
  __shared__ _Float16 Bs[128][40];
  int tid = threadIdx.x;
  int lane = tid & 63, wave = tid >> 6;
  int wm = (wave & 1) * 64, wn = (wave >> 1) * 64;
  int m0 = blockIdx.y * 128, n0 = blockIdx.x * 128;

  f32x4 acc[4][4] = {};

  int srow = tid >> 2;          // 0..63
  int scol = (tid & 3) * 8;     // 0,8,16,24
  int mq = lane & 15, quad = lane >> 4;

  for (int k0 = 0; k0 < K; k0 += 32) {
    *(half8*)&As[srow][scol]      = *(const half8*)(A  + (size_t)(m0 + srow) * K + k0 + scol);
    *(half8*)&As[srow + 64][scol] = *(const half8*)(A  + (size_t)(m0 + srow + 64) * K + k0 + scol);
    *(half8*)&Bs[srow][scol]      = *(const half8*)(BT + (size_t)(n0 + srow) * K + k0 + scol);
    *(half8*)&Bs[srow + 64][scol] = *(const half8*)(BT + (size_t)(n0 + srow + 64) * K + k0 + scol);
    __syncthreads();
    half8 af[4], bf[4];
#pragma unroll
    for (int t4 = 0; t4 < 4; ++t4) {
      af[t4] = *(const half8*)&As[wm + t4 * 16 + mq][quad * 8];
      bf[t4] = *(const half8*)&Bs[wn + t4 * 16 + mq][quad * 8];
    }
#pragma unroll
    for (int mt = 0; mt < 4; ++mt)
#pragma unroll
      for (int nt = 0; nt < 4; ++nt)
        acc[mt][nt] = __builtin_amdgcn_mfma_f32_16x16x32_f16(af[mt], bf[nt], acc[mt][nt], 0, 0, 0);
    __syncthreads();
  }

#pragma unroll
  for (int mt = 0; mt < 4; ++mt)
#pragma unroll
    for (int nt = 0; nt < 4; ++nt) {
      int n = n0 + wn + nt * 16 + mq;
      float bb = bias ? bias[n] : 0.f;
#pragma unroll
      for (int r = 0; r < 4; ++r) {
        int m = m0 + wm + mt * 16 + quad * 4 + r;
        C[(size_t)m * N + n] = acc[mt][nt][r] + bb;
      }
    }
}

// ---------- in-place RoPE on x[s][h*128+d], H heads ----------
__global__ void rope_simple(float* __restrict__ x, const float* __restrict__ cosb,
                            const float* __restrict__ sinb, int H) {
  int idx = blockIdx.x * 256 + threadIdx.x;
  int total = SEQ * H * 64;
  if (idx >= total) return;
  int d = idx & 63;
  int rest = idx >> 6;
  int h = rest % H;
  int s = rest / H;
  float* p = x + (size_t)s * (H * 128) + h * 128;
  float x1 = p[d], x2 = p[d + 64];
  float c1 = cosb[(size_t)s * 128 + d];
  float c2 = cosb[(size_t)s * 128 + d + 64];
  float s1 = sinb[(size_t)s * 128 + d];
  float s2 = sinb[(size_t)s * 128 + d + 64];
  p[d]      = x1 * c1 - x2 * s1;
  p[d + 64] = x2 * c2 + x1 * s2;
}

// ---------- per-(h,i) causal row softmax stats ----------
__global__ __launch_bounds__(128) void rowstats2(
    const float* __restrict__ q, const float* __restrict__ k,
    float* __restrict__ rowm, float* __restrict__ rowl) {
  int i = blockIdx.x, h = blockIdx.y, t = threadIdx.x;
  int kvh = h >> 2;
  __shared__ float qv[128];
  __shared__ float sarr[SEQ];
  __shared__ float red[128];
  qv[t] = q[(size_t)i * 2048 + h * 128 + t];
  __syncthreads();
  float lm = -INFINITY;
  for (int j = t; j <= i; j += 128) {
    const float* kp = k + (size_t)j * 512 + kvh * 128;
    float dot = 0.f;
    for (int d = 0; d < 128; ++d) dot += qv[d] * kp[d];
    float sv = dot * SCALE;
    sarr[j] = sv;
    lm = fmaxf(lm, sv);
  }
  float mm = blockReduceMax128(lm, red, t);
  float ls = 0.f;
  for (int j = t; j <= i; j += 128) ls += expf(sarr[j] - mm);
  float ll = blockReduceSum128(ls, red, t);
  if (t == 0) { rowm[h * SEQ + i] = mm; rowl[h * SEQ + i] = ll; }
}

// ---------- colsum[h][j] = sum_i softmax(scores)[i][j] (f64 accumulate) ----------
__global__ __launch_bounds__(128) void colsum2(
    const float* __restrict__ q, const float* __restrict__ k,
    const float* __restrict__ rowm, const float* __restrict__ rowl,
    float* __restrict__ colsum) {
  int j = blockIdx.x, h = blockIdx.y, t = threadIdx.x;
  int kvh = h >> 2;
  __shared__ float kv[128];
  __shared__ double redd[128];
  kv[t] = k[(size_t)j * 512 + kvh * 128 + t];
  __syncthreads();
  double ps = 0.0;
  for (int i = j + t; i < SEQ; i += 128) {
    const float* qp = q + (size_t)i * 2048 + h * 128;
    float dot = 0.f;
    for (int d = 0; d < 128; ++d) dot += kv[d] * qp[d];
    ps += (double)(expf(dot * SCALE - rowm[h * SEQ + i]) / rowl[h * SEQ + i]);
  }
  redd[t] = ps; __syncthreads();
  for (int s = 64; s > 0; s >>= 1) {
    if (t < s) redd[t] += redd[t + s];
    __syncthreads();
  }
  if (t == 0) colsum[h * SEQ + j] = (float)redd[0];
}

// ---------- top-HEAVY per head (iterative argmax, lowest-index ties) ----------
__global__ __launch_bounds__(64) void topk_k(const float* __restrict__ colsum,
                                             int* __restrict__ hidx) {
  int h = blockIdx.x, t = threadIdx.x;
  __shared__ float vals[SEQ];
  for (int j = t; j < SEQ; j += 64) vals[j] = colsum[h * SEQ + j];
  __syncthreads();
  for (int it = 0; it < HEAVY; ++it) {
    float bv = -INFINITY; int bi = SEQ - 1;
    for (int j = t; j < SEQ; j += 64) {
      float v = vals[j];
      if (v > bv) { bv = v; bi = j; }
    }
    for (int off = 32; off > 0; off >>= 1) {
      float ov = __shfl_xor(bv, off, 64);
      int   oi = __shfl_xor(bi, off, 64);
      if (ov > bv || (ov == bv && oi < bi)) { bv = ov; bi = oi; }
    }
    bi = min(max(bi, 0), SEQ - 1);
    if (t == 0) hidx[h * HEAVY + it] = bi;
    __syncthreads();
    vals[bi] = -INFINITY;
    __syncthreads();
  }
}

// ---------- sparse attention over heavy ∪ recent band, online softmax ----------
__global__ __launch_bounds__(128) void attn2(
    const float* __restrict__ q, const float* __restrict__ k,
    const float* __restrict__ v, const int* __restrict__ hidx,
    _Float16* __restrict__ ctx) {
  int i = blockIdx.x, h = blockIdx.y, t = threadIdx.x;
  int kvh = h >> 2;
  __shared__ float qv[128];
  __shared__ float sp[128];
  __shared__ int jarr[128];
  __shared__ float red[128];
  qv[t] = q[(size_t)i * 2048 + h * 128 + t];
  __syncthreads();

  float m = -INFINITY, l = 0.f, acc = 0.f;
  int jb0 = max(0, i - RECENT);
  int nbc = (i - jb0 + 1 + 127) >> 7;
  int total = 2 + nbc;

  for (int c = 0; c < total; ++c) {
    int j = 0; bool use = false;
    if (c < 2) {
      int idx = c * 128 + t;
      if (idx < HEAVY) {
        int jj = hidx[h * HEAVY + idx];
        if (jj < jb0) { j = jj; use = true; }
      }
    } else {
      int jj = jb0 + (c - 2) * 128 + t;
      if (jj <= i) { j = jj; use = true; }
    }
    float s = -INFINITY;
    if (use) {
      const float* kp = k + (size_t)j * 512 + kvh * 128;
      float dot = 0.f;
      for (int d = 0; d < 128; ++d) dot += qv[d] * kp[d];
      s = dot * SCALE;
    }
    float cm = blockReduceMax128(s, red, t);
    if (cm == -INFINITY) continue;
    float nm = fmaxf(m, cm);
    float alpha = (m == -INFINITY) ? 0.f : expf(m - nm);
    float p = use ? expf(s - nm) : 0.f;
    sp[t] = p; jarr[t] = use ? j : 0;
    float csum = blockReduceSum128(p, red, t);
    l = l * alpha + csum;
    m = nm;
    acc *= alpha;
    const float* vb = v + (size_t)kvh * 128 + t;
    for (int jj2 = 0; jj2 < 128; ++jj2) {
      float pj = sp[jj2];
      if (pj > 0.f) acc += pj * vb[(size_t)jarr[jj2] * 512];
    }
    __syncthreads();
  }
  ctx[(size_t)i * 2048 + h * 128 + t] = (_Float16)(acc / l);
}

// ---------- launch ----------
extern "C" void kernel_launch(void* const* d_in, const int* in_sizes, int n_in,
                              void* d_out, int out_size, void* d_ws, size_t ws_size,
                              hipStream_t stream) {
  const float* hs   = (const float*)d_in[0];
  const float* cosb = (const float*)d_in[1];
  const float* sinb = (const float*)d_in[2];
  // d_in[3] = attention_mask (pure causal) -- analytic
  const float* Wq = (const float*)d_in[4];
  const float* bq = (const float*)d_in[5];
  const float* Wk = (const float*)d_in[6];
  const float* bk = (const float*)d_in[7];
  const float* Wv = (const float*)d_in[8];
  const float* bv = (const float*)d_in[9];
  const float* Wo = (const float*)d_in[10];
  float* out = (float*)d_out;

  char* ws = (char*)d_ws;
  float* q    = (float*)ws;                               // [2048][2048] 16 MB
  _Float16* WkT = (_Float16*)ws;                          // [512][2048] f16 2 MB (dead before q written)
  _Float16* WvT = (_Float16*)(ws + (2u << 20));           // [512][2048] f16 2 MB (dead before q written)
  float* kbuf = q + (size_t)SEQ * 2048;                   // [2048][512]  4 MB  @16M
  float* vbuf = kbuf + (size_t)SEQ * 512;                 // [2048][512]  4 MB  @20M
  float* rowm = vbuf + (size_t)SEQ * 512;                 // @24M
  float* rowl = rowm + NH * SEQ;
  float* colsum = rowl + NH * SEQ;
  int*   hidx   = (int*)(colsum + NH * SEQ);
  _Float16* hsH = (_Float16*)(ws + (25u << 20));          // [2048][2048] f16 8 MB
  _Float16* WoT = (_Float16*)(ws + (33u << 20));          // [2048][2048] f16 8 MB
  _Float16* WqT = (_Float16*)(ws + (41u << 20));          // [2048][2048] f16 8 MB
  _Float16* ctxH = WqT;                                   // reuse after Q-gemm
  // total ~49 MB

  // converts + transposes
  cvt_h<<<(SEQ * 2048 / 4 + 255) / 256, 256, 0, stream>>>(hs, hsH, SEQ * 2048);
  transpose_h<<<dim3(512 / 64, 2048 / 64), 256, 0, stream>>>(Wk, WkT, 2048, 512);
  transpose_h<<<dim3(512 / 64, 2048 / 64), 256, 0, stream>>>(Wv, WvT, 2048, 512);
  transpose_h<<<dim3(2048 / 64, 2048 / 64), 256, 0, stream>>>(Wo, WoT, 2048, 2048);
  transpose_h<<<dim3(2048 / 64, 2048 / 64), 256, 0, stream>>>(Wq, WqT, 2048, 2048);

  // K, V projections first (they use buffers aliased with q), then Q
  gemm_h<<<dim3(512 / 128, 2048 / 128), 256, 0, stream>>>(hsH, WkT, bk, kbuf, SEQ, 512, 2048);
  gemm_h<<<dim3(512 / 128, 2048 / 128), 256, 0, stream>>>(hsH, WvT, bv, vbuf, SEQ, 512, 2048);
  gemm_h<<<dim3(2048 / 128, 2048 / 128), 256, 0, stream>>>(hsH, WqT, bq, q, SEQ, 2048, 2048);

  // RoPE in place
  rope_simple<<<(SEQ * 16 * 64 + 255) / 256, 256, 0, stream>>>(q,    cosb, sinb, 16);
  rope_simple<<<(SEQ * 4 * 64 + 255) / 256, 256, 0, stream>>>(kbuf, cosb, sinb, 4);

  // softmax row stats, column sums, top-k, sparse attention
  rowstats2<<<dim3(SEQ, NH), 128, 0, stream>>>(q, kbuf, rowm, rowl);
  colsum2<<<dim3(SEQ, NH), 128, 0, stream>>>(q, kbuf, rowm, rowl, colsum);
  topk_k<<<NH, 64, 0, stream>>>(colsum, hidx);
  attn2<<<dim3(SEQ, NH), 128, 0, stream>>>(q, kbuf, vbuf, hidx, ctxH);

  // output projection: ctxH(f16) @ Wo -> f32 out
  gemm_h<<<dim3(2048 / 128, 2048 / 128), 256, 0, stream>>>(ctxH, WoT, (const float*)nullptr,
                                                           out, SEQ, 2048, 2048);
}

// Round 7
// 1749.127 us; speedup vs baseline: 8.9473x; 3.3697x over previous
//
#include <hip/hip_runtime.h>
#include <hip/hip_bf16.h>
#include <math.h>

constexpr int SEQ    = 2048;
constexpr int NH     = 16;
constexpr int HEAVY  = 204;   // int(0.1*2048)
constexpr int RECENT = 204;   // int(0.1*2048)
constexpr float SCALE = 0.08838834764831845f; // 128^-0.5

typedef _Float16 half8 __attribute__((ext_vector_type(8)));
typedef float f32x4 __attribute__((ext_vector_type(4)));

__device__ __forceinline__ float blockReduceMax128(float v, float* red, int t) {
  red[t] = v; __syncthreads();
  for (int s = 64; s > 0; s >>= 1) {
    if (t < s) red[t] = fmaxf(red[t], red[t + s]);
    __syncthreads();
  }
  float r = red[0]; __syncthreads();
  return r;
}
__device__ __forceinline__ float blockReduceSum128(float v, float* red, int t) {
  red[t] = v; __syncthreads();
  for (int s = 64; s > 0; s >>= 1) {
    if (t < s) red[t] = red[t] + red[t + s];
    __syncthreads();
  }
  float r = red[0]; __syncthreads();
  return r;
}

// ---------- f32 -> f16 convert ----------
__global__ void cvt_h(const float* __restrict__ src, _Float16* __restrict__ dst, int n) {
  int i = (blockIdx.x * 256 + threadIdx.x) * 4;
  if (i + 3 < n) {
    float4 v = *(const float4*)(src + i);
    dst[i] = (_Float16)v.x; dst[i+1] = (_Float16)v.y;
    dst[i+2] = (_Float16)v.z; dst[i+3] = (_Float16)v.w;
  } else {
    for (int u = i; u < n; ++u) dst[u] = (_Float16)src[u];
  }
}

// ---------- transpose + convert: W f32 [K][N] -> WT f16 [N][K] ----------
__global__ __launch_bounds__(256) void transpose_h(
    const float* __restrict__ W, _Float16* __restrict__ WT, int K, int N) {
  __shared__ float T[64][65];
  int c = threadIdx.x & 63, rq = threadIdx.x >> 6;
  int n0 = blockIdx.x * 64, k0 = blockIdx.y * 64;
#pragma unroll
  for (int u = 0; u < 16; ++u) {
    int r = rq * 16 + u;
    T[r][c] = W[(size_t)(k0 + r) * N + n0 + c];
  }
  __syncthreads();
#pragma unroll
  for (int u = 0; u < 16; ++u) {
    int r = rq * 16 + u;
    WT[(size_t)(n0 + r) * K + k0 + c] = (_Float16)T[c][r];
  }
}

// ---------- MFMA f16 GEMM: C[m][n] = sum_k A[m][k]*BT[n][k] + bias[n] ----------
__global__ __launch_bounds__(256) void gemm_h(
    const _Float16* __restrict__ A, const _Float16* __restrict__ BT,
    const float* __restrict__ bias, float* __restrict__ C,
    int M, int N, int K)
{
  __shared__ _Float16 As[128][40];
  __shared__ _Float16 Bs[128][40];
  int tid = threadIdx.x;
  int lane = tid & 63, wave = tid >> 6;
  int wm = (wave & 1) * 64, wn = (wave >> 1) * 64;
  int m0 = blockIdx.y * 128, n0 = blockIdx.x * 128;

  f32x4 acc[4][4] = {};

  int srow = tid >> 2;
  int scol = (tid & 3) * 8;
  int mq = lane & 15, quad = lane >> 4;

  for (int k0 = 0; k0 < K; k0 += 32) {
    *(half8*)&As[srow][scol]      = *(const half8*)(A  + (size_t)(m0 + srow) * K + k0 + scol);
    *(half8*)&As[srow + 64][scol] = *(const half8*)(A  + (size_t)(m0 + srow + 64) * K + k0 + scol);
    *(half8*)&Bs[srow][scol]      = *(const half8*)(BT + (size_t)(n0 + srow) * K + k0 + scol);
    *(half8*)&Bs[srow + 64][scol] = *(const half8*)(BT + (size_t)(n0 + srow + 64) * K + k0 + scol);
    __syncthreads();
    half8 af[4], bf[4];
#pragma unroll
    for (int t4 = 0; t4 < 4; ++t4) {
      af[t4] = *(const half8*)&As[wm + t4 * 16 + mq][quad * 8];
      bf[t4] = *(const half8*)&Bs[wn + t4 * 16 + mq][quad * 8];
    }
#pragma unroll
    for (int mt = 0; mt < 4; ++mt)
#pragma unroll
      for (int nt = 0; nt < 4; ++nt)
        acc[mt][nt] = __builtin_amdgcn_mfma_f32_16x16x32_f16(af[mt], bf[nt], acc[mt][nt], 0, 0, 0);
    __syncthreads();
  }

#pragma unroll
  for (int mt = 0; mt < 4; ++mt)
#pragma unroll
    for (int nt = 0; nt < 4; ++nt) {
      int n = n0 + wn + nt * 16 + mq;
      float bb = bias ? bias[n] : 0.f;
#pragma unroll
      for (int r = 0; r < 4; ++r) {
        int m = m0 + wm + mt * 16 + quad * 4 + r;
        C[(size_t)m * N + n] = acc[mt][nt][r] + bb;
      }
    }
}

// ---------- in-place RoPE + f16 emit ----------
__global__ void rope_simple(float* __restrict__ x, const float* __restrict__ cosb,
                            const float* __restrict__ sinb, int H,
                            _Float16* __restrict__ xh) {
  int idx = blockIdx.x * 256 + threadIdx.x;
  int total = SEQ * H * 64;
  if (idx >= total) return;
  int d = idx & 63;
  int rest = idx >> 6;
  int h = rest % H;
  int s = rest / H;
  size_t base = (size_t)s * (H * 128) + h * 128;
  float* p = x + base;
  _Float16* ph = xh + base;
  float x1 = p[d], x2 = p[d + 64];
  float c1 = cosb[(size_t)s * 128 + d];
  float c2 = cosb[(size_t)s * 128 + d + 64];
  float s1 = sinb[(size_t)s * 128 + d];
  float s2 = sinb[(size_t)s * 128 + d + 64];
  float o1 = x1 * c1 - x2 * s1;
  float o2 = x2 * c2 + x1 * s2;
  p[d] = o1; p[d + 64] = o2;
  ph[d] = (_Float16)o1; ph[d + 64] = (_Float16)o2;
}

// ---------- S1: MFMA flash row stats (m_i, l_i) over causal scores ----------
__global__ __launch_bounds__(256) void flashstats(
    const _Float16* __restrict__ qh, const _Float16* __restrict__ kh,
    float* __restrict__ rowm, float* __restrict__ rowl)
{
  int i0 = blockIdx.x * 128, h = blockIdx.y, kvh = h >> 2;
  __shared__ _Float16 Qs[128][136];
  __shared__ _Float16 Ks[128][136];
  int tid = threadIdx.x, lane = tid & 63, wave = tid >> 6;
  int mq = lane & 15, quad = lane >> 4;
  int wm = wave * 32;

#pragma unroll
  for (int u = 0; u < 8; ++u) {
    int unit = u * 256 + tid;            // 0..2047
    int r = unit >> 4, c8 = (unit & 15) * 8;
    *(half8*)&Qs[r][c8] = *(const half8*)(qh + (size_t)(i0 + r) * 2048 + h * 128 + c8);
  }

  float runm[2][4], runl[2][4];
#pragma unroll
  for (int rt = 0; rt < 2; ++rt)
#pragma unroll
    for (int r = 0; r < 4; ++r) { runm[rt][r] = -INFINITY; runl[rt][r] = 0.f; }

  int nblk = i0 / 128 + 1;
  for (int jb = 0; jb < nblk; ++jb) {
    int j0 = jb * 128;
    __syncthreads();
#pragma unroll
    for (int u = 0; u < 8; ++u) {
      int unit = u * 256 + tid;
      int r = unit >> 4, c8 = (unit & 15) * 8;
      *(half8*)&Ks[r][c8] = *(const half8*)(kh + (size_t)(j0 + r) * 512 + kvh * 128 + c8);
    }
    __syncthreads();

    f32x4 acc[2][8] = {};
#pragma unroll
    for (int ks = 0; ks < 4; ++ks) {
      half8 af[2], bf[8];
#pragma unroll
      for (int rt = 0; rt < 2; ++rt) af[rt] = *(const half8*)&Qs[wm + rt * 16 + mq][ks * 32 + quad * 8];
#pragma unroll
      for (int ct = 0; ct < 8; ++ct) bf[ct] = *(const half8*)&Ks[ct * 16 + mq][ks * 32 + quad * 8];
#pragma unroll
      for (int rt = 0; rt < 2; ++rt)
#pragma unroll
        for (int ct = 0; ct < 8; ++ct)
          acc[rt][ct] = __builtin_amdgcn_mfma_f32_16x16x32_f16(af[rt], bf[ct], acc[rt][ct], 0, 0, 0);
    }

#pragma unroll
    for (int rt = 0; rt < 2; ++rt) {
      int rbase = i0 + wm + rt * 16 + quad * 4;
#pragma unroll
      for (int ct = 0; ct < 8; ++ct) {
        int j = j0 + ct * 16 + mq;
#pragma unroll
        for (int r = 0; r < 4; ++r) {
          float s = acc[rt][ct][r] * SCALE;
          if (j > rbase + r) s = -INFINITY;
          acc[rt][ct][r] = s;
        }
      }
#pragma unroll
      for (int r = 0; r < 4; ++r) {
        float v = acc[rt][0][r];
#pragma unroll
        for (int ct = 1; ct < 8; ++ct) v = fmaxf(v, acc[rt][ct][r]);
        for (int off = 1; off < 16; off <<= 1) v = fmaxf(v, __shfl_xor(v, off, 64));
        float nm = fmaxf(runm[rt][r], v);
        float alpha = (runm[rt][r] == -INFINITY) ? 0.f : __expf(runm[rt][r] - nm);
        float ps = 0.f;
#pragma unroll
        for (int ct = 0; ct < 8; ++ct) ps += __expf(acc[rt][ct][r] - nm);
        for (int off = 1; off < 16; off <<= 1) ps += __shfl_xor(ps, off, 64);
        runl[rt][r] = runl[rt][r] * alpha + ps;
        runm[rt][r] = nm;
      }
    }
  }
  if (mq == 0) {
#pragma unroll
    for (int rt = 0; rt < 2; ++rt)
#pragma unroll
      for (int r = 0; r < 4; ++r) {
        int i = i0 + wm + rt * 16 + quad * 4 + r;
        rowm[h * SEQ + i] = runm[rt][r];
        rowl[h * SEQ + i] = runl[rt][r];
      }
  }
}

// ---------- S2: MFMA colsum[h][j] = sum_i exp(s_ij - m_i)/l_i ----------
__global__ __launch_bounds__(256) void flashcolsum(
    const _Float16* __restrict__ qh, const _Float16* __restrict__ kh,
    const float* __restrict__ rowm, const float* __restrict__ rowl,
    float* __restrict__ colsum)
{
  int j0 = blockIdx.x * 128, h = blockIdx.y, kvh = h >> 2;
  __shared__ _Float16 Qs[128][136];
  __shared__ _Float16 Ks[128][136];
  __shared__ float colred[4][128];
  int tid = threadIdx.x, lane = tid & 63, wave = tid >> 6;
  int mq = lane & 15, quad = lane >> 4;
  int wm = wave * 32;

#pragma unroll
  for (int u = 0; u < 8; ++u) {
    int unit = u * 256 + tid;
    int r = unit >> 4, c8 = (unit & 15) * 8;
    *(half8*)&Ks[r][c8] = *(const half8*)(kh + (size_t)(j0 + r) * 512 + kvh * 128 + c8);
  }

  float colacc[8] = {};
  for (int ib = j0 / 128; ib < SEQ / 128; ++ib) {
    int i0 = ib * 128;
    __syncthreads();
#pragma unroll
    for (int u = 0; u < 8; ++u) {
      int unit = u * 256 + tid;
      int r = unit >> 4, c8 = (unit & 15) * 8;
      *(half8*)&Qs[r][c8] = *(const half8*)(qh + (size_t)(i0 + r) * 2048 + h * 128 + c8);
    }
    __syncthreads();

    f32x4 acc[2][8] = {};
#pragma unroll
    for (int ks = 0; ks < 4; ++ks) {
      half8 af[2], bf[8];
#pragma unroll
      for (int rt = 0; rt < 2; ++rt) af[rt] = *(const half8*)&Qs[wm + rt * 16 + mq][ks * 32 + quad * 8];
#pragma unroll
      for (int ct = 0; ct < 8; ++ct) bf[ct] = *(const half8*)&Ks[ct * 16 + mq][ks * 32 + quad * 8];
#pragma unroll
      for (int rt = 0; rt < 2; ++rt)
#pragma unroll
        for (int ct = 0; ct < 8; ++ct)
          acc[rt][ct] = __builtin_amdgcn_mfma_f32_16x16x32_f16(af[rt], bf[ct], acc[rt][ct], 0, 0, 0);
    }

#pragma unroll
    for (int rt = 0; rt < 2; ++rt) {
      int rbase = i0 + wm + rt * 16 + quad * 4;
      float rm[4], ri[4];
#pragma unroll
      for (int r = 0; r < 4; ++r) {
        rm[r] = rowm[h * SEQ + rbase + r];
        ri[r] = 1.f / rowl[h * SEQ + rbase + r];
      }
#pragma unroll
      for (int ct = 0; ct < 8; ++ct) {
        int j = j0 + ct * 16 + mq;
        float cp = 0.f;
#pragma unroll
        for (int r = 0; r < 4; ++r) {
          if (j <= rbase + r)
            cp += __expf(acc[rt][ct][r] * SCALE - rm[r]) * ri[r];
        }
        colacc[ct] += cp;
      }
    }
  }
#pragma unroll
  for (int ct = 0; ct < 8; ++ct) {
    float v = colacc[ct];
    v += __shfl_xor(v, 16, 64);
    v += __shfl_xor(v, 32, 64);
    colacc[ct] = v;
  }
  __syncthreads();
  if (quad == 0) {
#pragma unroll
    for (int ct = 0; ct < 8; ++ct) colred[wave][ct * 16 + mq] = colacc[ct];
  }
  __syncthreads();
  if (tid < 128)
    colsum[h * SEQ + j0 + tid] =
        colred[0][tid] + colred[1][tid] + colred[2][tid] + colred[3][tid];
}

// ---------- top-HEAVY per head ----------
__global__ __launch_bounds__(64) void topk_k(const float* __restrict__ colsum,
                                             int* __restrict__ hidx) {
  int h = blockIdx.x, t = threadIdx.x;
  __shared__ float vals[SEQ];
  for (int j = t; j < SEQ; j += 64) vals[j] = colsum[h * SEQ + j];
  __syncthreads();
  for (int it = 0; it < HEAVY; ++it) {
    float bv = -INFINITY; int bi = SEQ - 1;
    for (int j = t; j < SEQ; j += 64) {
      float v = vals[j];
      if (v > bv) { bv = v; bi = j; }
    }
    for (int off = 32; off > 0; off >>= 1) {
      float ov = __shfl_xor(bv, off, 64);
      int   oi = __shfl_xor(bi, off, 64);
      if (ov > bv || (ov == bv && oi < bi)) { bv = ov; bi = oi; }
    }
    bi = min(max(bi, 0), SEQ - 1);
    if (t == 0) hidx[h * HEAVY + it] = bi;
    __syncthreads();
    vals[bi] = -INFINITY;
    __syncthreads();
  }
}

// ---------- sparse attention (f16 K loads) ----------
__global__ __launch_bounds__(128) void attn2(
    const float* __restrict__ q, const _Float16* __restrict__ kh,
    const float* __restrict__ v, const int* __restrict__ hidx,
    _Float16* __restrict__ ctx) {
  int i = blockIdx.x, h = blockIdx.y, t = threadIdx.x;
  int kvh = h >> 2;
  __shared__ float qv[128];
  __shared__ float sp[128];
  __shared__ int jarr[128];
  __shared__ float red[128];
  qv[t] = q[(size_t)i * 2048 + h * 128 + t];
  __syncthreads();

  float m = -INFINITY, l = 0.f, acc = 0.f;
  int jb0 = max(0, i - RECENT);
  int nbc = (i - jb0 + 1 + 127) >> 7;
  int total = 2 + nbc;

  for (int c = 0; c < total; ++c) {
    int j = 0; bool use = false;
    if (c < 2) {
      int idx = c * 128 + t;
      if (idx < HEAVY) {
        int jj = hidx[h * HEAVY + idx];
        if (jj < jb0) { j = jj; use = true; }
      }
    } else {
      int jj = jb0 + (c - 2) * 128 + t;
      if (jj <= i) { j = jj; use = true; }
    }
    float s = -INFINITY;
    if (use) {
      const _Float16* kp = kh + (size_t)j * 512 + kvh * 128;
      float dot = 0.f;
#pragma unroll
      for (int u = 0; u < 16; ++u) {
        half8 k8 = *(const half8*)(kp + u * 8);
#pragma unroll
        for (int e = 0; e < 8; ++e) dot += qv[u * 8 + e] * (float)k8[e];
      }
      s = dot * SCALE;
    }
    float cm = blockReduceMax128(s, red, t);
    if (cm == -INFINITY) continue;
    float nm = fmaxf(m, cm);
    float alpha = (m == -INFINITY) ? 0.f : __expf(m - nm);
    float p = use ? __expf(s - nm) : 0.f;
    sp[t] = p; jarr[t] = use ? j : 0;
    float csum = blockReduceSum128(p, red, t);
    l = l * alpha + csum;
    m = nm;
    acc *= alpha;
    const float* vb = v + (size_t)kvh * 128 + t;
    for (int jj2 = 0; jj2 < 128; ++jj2) {
      float pj = sp[jj2];
      if (pj > 0.f) acc += pj * vb[(size_t)jarr[jj2] * 512];
    }
    __syncthreads();
  }
  ctx[(size_t)i * 2048 + h * 128 + t] = (_Float16)(acc / l);
}

// ---------- launch ----------
extern "C" void kernel_launch(void* const* d_in, const int* in_sizes, int n_in,
                              void* d_out, int out_size, void* d_ws, size_t ws_size,
                              hipStream_t stream) {
  const float* hs   = (const float*)d_in[0];
  const float* cosb = (const float*)d_in[1];
  const float* sinb = (const float*)d_in[2];
  const float* Wq = (const float*)d_in[4];
  const float* bq = (const float*)d_in[5];
  const float* Wk = (const float*)d_in[6];
  const float* bk = (const float*)d_in[7];
  const float* Wv = (const float*)d_in[8];
  const float* bv = (const float*)d_in[9];
  const float* Wo = (const float*)d_in[10];
  float* out = (float*)d_out;

  char* ws = (char*)d_ws;
  float* q    = (float*)ws;                               // [2048][2048] 16 MB @0
  _Float16* WkT = (_Float16*)ws;                          // 2 MB (dead before q written)
  _Float16* WvT = (_Float16*)(ws + (2u << 20));           // 2 MB (dead before q written)
  float* kbuf = q + (size_t)SEQ * 2048;                   // [2048][512] 4 MB @16M
  float* vbuf = kbuf + (size_t)SEQ * 512;                 // [2048][512] 4 MB @20M
  float* rowm = vbuf + (size_t)SEQ * 512;                 // @24M
  float* rowl = rowm + NH * SEQ;
  float* colsum = rowl + NH * SEQ;
  int*   hidx   = (int*)(colsum + NH * SEQ);
  _Float16* hsH = (_Float16*)(ws + (25u << 20));          // 8 MB @25M
  _Float16* qh  = hsH;                                    // reuse after Q gemm
  _Float16* WoT = (_Float16*)(ws + (33u << 20));          // 8 MB @33M
  _Float16* WqT = (_Float16*)(ws + (41u << 20));          // 8 MB @41M
  _Float16* ctxH = WqT;                                   // reuse after Q gemm
  _Float16* kh  = (_Float16*)(ws + (49u << 20));          // [2048][512] f16 2 MB @49M
  // total ~51 MB

  cvt_h<<<(SEQ * 2048 / 4 + 255) / 256, 256, 0, stream>>>(hs, hsH, SEQ * 2048);
  transpose_h<<<dim3(512 / 64, 2048 / 64), 256, 0, stream>>>(Wk, WkT, 2048, 512);
  transpose_h<<<dim3(512 / 64, 2048 / 64), 256, 0, stream>>>(Wv, WvT, 2048, 512);
  transpose_h<<<dim3(2048 / 64, 2048 / 64), 256, 0, stream>>>(Wo, WoT, 2048, 2048);
  transpose_h<<<dim3(2048 / 64, 2048 / 64), 256, 0, stream>>>(Wq, WqT, 2048, 2048);

  gemm_h<<<dim3(512 / 128, 2048 / 128), 256, 0, stream>>>(hsH, WkT, bk, kbuf, SEQ, 512, 2048);
  gemm_h<<<dim3(512 / 128, 2048 / 128), 256, 0, stream>>>(hsH, WvT, bv, vbuf, SEQ, 512, 2048);
  gemm_h<<<dim3(2048 / 128, 2048 / 128), 256, 0, stream>>>(hsH, WqT, bq, q, SEQ, 2048, 2048);

  // RoPE in place + f16 copies (qh overwrites hsH region -- hsH consumed by now)
  rope_simple<<<(SEQ * 16 * 64 + 255) / 256, 256, 0, stream>>>(q,    cosb, sinb, 16, qh);
  rope_simple<<<(SEQ * 4 * 64 + 255) / 256, 256, 0, stream>>>(kbuf, cosb, sinb, 4,  kh);

  flashstats<<<dim3(SEQ / 128, NH), 256, 0, stream>>>(qh, kh, rowm, rowl);
  flashcolsum<<<dim3(SEQ / 128, NH), 256, 0, stream>>>(qh, kh, rowm, rowl, colsum);
  topk_k<<<NH, 64, 0, stream>>>(colsum, hidx);
  attn2<<<dim3(SEQ, NH), 128, 0, stream>>>(q, kh, vbuf, hidx, ctxH);

  gemm_h<<<dim3(2048 / 128, 2048 / 128), 256, 0, stream>>>(ctxH, WoT, (const float*)nullptr,
                                                           out, SEQ, 2048, 2048);
}

// Round 8
// 903.439 us; speedup vs baseline: 17.3227x; 1.9361x over previous
//
#include <hip/hip_runtime.h>
#include <hip/hip_bf16.h>
#include <math.h>

constexpr int SEQ    = 2048;
constexpr int NH     = 16;
constexpr int HEAVY  = 204;   // int(0.1*2048)
constexpr int RECENT = 204;   // int(0.1*2048)
constexpr float SCALE = 0.08838834764831845f; // 128^-0.5

typedef _Float16 half8 __attribute__((ext_vector_type(8)));
typedef float f32x4 __attribute__((ext_vector_type(4)));

// ---------- f32 -> f16 convert ----------
__global__ void cvt_h(const float* __restrict__ src, _Float16* __restrict__ dst, int n) {
  int i = (blockIdx.x * 256 + threadIdx.x) * 4;
  if (i + 3 < n) {
    float4 v = *(const float4*)(src + i);
    dst[i] = (_Float16)v.x; dst[i+1] = (_Float16)v.y;
    dst[i+2] = (_Float16)v.z; dst[i+3] = (_Float16)v.w;
  } else {
    for (int u = i; u < n; ++u) dst[u] = (_Float16)src[u];
  }
}

// ---------- transpose + convert: W f32 [K][N] -> WT f16 [N][K] ----------
__global__ __launch_bounds__(256) void transpose_h(
    const float* __restrict__ W, _Float16* __restrict__ WT, int K, int N) {
  __shared__ float T[64][65];
  int c = threadIdx.x & 63, rq = threadIdx.x >> 6;
  int n0 = blockIdx.x * 64, k0 = blockIdx.y * 64;
#pragma unroll
  for (int u = 0; u < 16; ++u) {
    int r = rq * 16 + u;
    T[r][c] = W[(size_t)(k0 + r) * N + n0 + c];
  }
  __syncthreads();
#pragma unroll
  for (int u = 0; u < 16; ++u) {
    int r = rq * 16 + u;
    WT[(size_t)(n0 + r) * K + k0 + c] = (_Float16)T[c][r];
  }
}

// ---------- MFMA f16 GEMM: C[m][n] = sum_k A[m][k]*BT[n][k] + bias[n] ----------
__global__ __launch_bounds__(256) void gemm_h(
    const _Float16* __restrict__ A, const _Float16* __restrict__ BT,
    const float* __restrict__ bias, float* __restrict__ C,
    int M, int N, int K)
{
  __shared__ _Float16 As[128][40];
  __shared__ _Float16 Bs[128][40];
  int tid = threadIdx.x;
  int lane = tid & 63, wave = tid >> 6;
  int wm = (wave & 1) * 64, wn = (wave >> 1) * 64;
  int m0 = blockIdx.y * 128, n0 = blockIdx.x * 128;

  f32x4 acc[4][4] = {};

  int srow = tid >> 2;
  int scol = (tid & 3) * 8;
  int mq = lane & 15, quad = lane >> 4;

  for (int k0 = 0; k0 < K; k0 += 32) {
    *(half8*)&As[srow][scol]      = *(const half8*)(A  + (size_t)(m0 + srow) * K + k0 + scol);
    *(half8*)&As[srow + 64][scol] = *(const half8*)(A  + (size_t)(m0 + srow + 64) * K + k0 + scol);
    *(half8*)&Bs[srow][scol]      = *(const half8*)(BT + (size_t)(n0 + srow) * K + k0 + scol);
    *(half8*)&Bs[srow + 64][scol] = *(const half8*)(BT + (size_t)(n0 + srow + 64) * K + k0 + scol);
    __syncthreads();
    half8 af[4], bf[4];
#pragma unroll
    for (int t4 = 0; t4 < 4; ++t4) {
      af[t4] = *(const half8*)&As[wm + t4 * 16 + mq][quad * 8];
      bf[t4] = *(const half8*)&Bs[wn + t4 * 16 + mq][quad * 8];
    }
#pragma unroll
    for (int mt = 0; mt < 4; ++mt)
#pragma unroll
      for (int nt = 0; nt < 4; ++nt)
        acc[mt][nt] = __builtin_amdgcn_mfma_f32_16x16x32_f16(af[mt], bf[nt], acc[mt][nt], 0, 0, 0);
    __syncthreads();
  }

#pragma unroll
  for (int mt = 0; mt < 4; ++mt)
#pragma unroll
    for (int nt = 0; nt < 4; ++nt) {
      int n = n0 + wn + nt * 16 + mq;
      float bb = bias ? bias[n] : 0.f;
#pragma unroll
      for (int r = 0; r < 4; ++r) {
        int m = m0 + wm + mt * 16 + quad * 4 + r;
        C[(size_t)m * N + n] = acc[mt][nt][r] + bb;
      }
    }
}

// ---------- in-place RoPE + f16 emit ----------
__global__ void rope_simple(float* __restrict__ x, const float* __restrict__ cosb,
                            const float* __restrict__ sinb, int H,
                            _Float16* __restrict__ xh) {
  int idx = blockIdx.x * 256 + threadIdx.x;
  int total = SEQ * H * 64;
  if (idx >= total) return;
  int d = idx & 63;
  int rest = idx >> 6;
  int h = rest % H;
  int s = rest / H;
  size_t base = (size_t)s * (H * 128) + h * 128;
  float* p = x + base;
  _Float16* ph = xh + base;
  float x1 = p[d], x2 = p[d + 64];
  float c1 = cosb[(size_t)s * 128 + d];
  float c2 = cosb[(size_t)s * 128 + d + 64];
  float s1 = sinb[(size_t)s * 128 + d];
  float s2 = sinb[(size_t)s * 128 + d + 64];
  float o1 = x1 * c1 - x2 * s1;
  float o2 = x2 * c2 + x1 * s2;
  p[d] = o1; p[d + 64] = o2;
  ph[d] = (_Float16)o1; ph[d + 64] = (_Float16)o2;
}

// ---------- S1: MFMA flash row stats (m_i, l_i) over causal scores ----------
__global__ __launch_bounds__(256) void flashstats(
    const _Float16* __restrict__ qh, const _Float16* __restrict__ kh,
    float* __restrict__ rowm, float* __restrict__ rowl)
{
  int i0 = blockIdx.x * 128, h = blockIdx.y, kvh = h >> 2;
  __shared__ _Float16 Qs[128][136];
  __shared__ _Float16 Ks[128][136];
  int tid = threadIdx.x, lane = tid & 63, wave = tid >> 6;
  int mq = lane & 15, quad = lane >> 4;
  int wm = wave * 32;

#pragma unroll
  for (int u = 0; u < 8; ++u) {
    int unit = u * 256 + tid;
    int r = unit >> 4, c8 = (unit & 15) * 8;
    *(half8*)&Qs[r][c8] = *(const half8*)(qh + (size_t)(i0 + r) * 2048 + h * 128 + c8);
  }

  float runm[2][4], runl[2][4];
#pragma unroll
  for (int rt = 0; rt < 2; ++rt)
#pragma unroll
    for (int r = 0; r < 4; ++r) { runm[rt][r] = -INFINITY; runl[rt][r] = 0.f; }

  int nblk = i0 / 128 + 1;
  for (int jb = 0; jb < nblk; ++jb) {
    int j0 = jb * 128;
    __syncthreads();
#pragma unroll
    for (int u = 0; u < 8; ++u) {
      int unit = u * 256 + tid;
      int r = unit >> 4, c8 = (unit & 15) * 8;
      *(half8*)&Ks[r][c8] = *(const half8*)(kh + (size_t)(j0 + r) * 512 + kvh * 128 + c8);
    }
    __syncthreads();

    f32x4 acc[2][8] = {};
#pragma unroll
    for (int ks = 0; ks < 4; ++ks) {
      half8 af[2], bf[8];
#pragma unroll
      for (int rt = 0; rt < 2; ++rt) af[rt] = *(const half8*)&Qs[wm + rt * 16 + mq][ks * 32 + quad * 8];
#pragma unroll
      for (int ct = 0; ct < 8; ++ct) bf[ct] = *(const half8*)&Ks[ct * 16 + mq][ks * 32 + quad * 8];
#pragma unroll
      for (int rt = 0; rt < 2; ++rt)
#pragma unroll
        for (int ct = 0; ct < 8; ++ct)
          acc[rt][ct] = __builtin_amdgcn_mfma_f32_16x16x32_f16(af[rt], bf[ct], acc[rt][ct], 0, 0, 0);
    }

#pragma unroll
    for (int rt = 0; rt < 2; ++rt) {
      int rbase = i0 + wm + rt * 16 + quad * 4;
#pragma unroll
      for (int ct = 0; ct < 8; ++ct) {
        int j = j0 + ct * 16 + mq;
#pragma unroll
        for (int r = 0; r < 4; ++r) {
          float s = acc[rt][ct][r] * SCALE;
          if (j > rbase + r) s = -INFINITY;
          acc[rt][ct][r] = s;
        }
      }
#pragma unroll
      for (int r = 0; r < 4; ++r) {
        float v = acc[rt][0][r];
#pragma unroll
        for (int ct = 1; ct < 8; ++ct) v = fmaxf(v, acc[rt][ct][r]);
        for (int off = 1; off < 16; off <<= 1) v = fmaxf(v, __shfl_xor(v, off, 64));
        float nm = fmaxf(runm[rt][r], v);
        float alpha = (runm[rt][r] == -INFINITY) ? 0.f : __expf(runm[rt][r] - nm);
        float ps = 0.f;
#pragma unroll
        for (int ct = 0; ct < 8; ++ct) ps += __expf(acc[rt][ct][r] - nm);
        for (int off = 1; off < 16; off <<= 1) ps += __shfl_xor(ps, off, 64);
        runl[rt][r] = runl[rt][r] * alpha + ps;
        runm[rt][r] = nm;
      }
    }
  }
  if (mq == 0) {
#pragma unroll
    for (int rt = 0; rt < 2; ++rt)
#pragma unroll
      for (int r = 0; r < 4; ++r) {
        int i = i0 + wm + rt * 16 + quad * 4 + r;
        rowm[h * SEQ + i] = runm[rt][r];
        rowl[h * SEQ + i] = runl[rt][r];
      }
  }
}

// ---------- S2: MFMA colsum[h][j] = sum_i exp(s_ij - m_i)/l_i ----------
__global__ __launch_bounds__(256) void flashcolsum(
    const _Float16* __restrict__ qh, const _Float16* __restrict__ kh,
    const float* __restrict__ rowm, const float* __restrict__ rowl,
    float* __restrict__ colsum)
{
  int j0 = blockIdx.x * 128, h = blockIdx.y, kvh = h >> 2;
  __shared__ _Float16 Qs[128][136];
  __shared__ _Float16 Ks[128][136];
  __shared__ float colred[4][128];
  int tid = threadIdx.x, lane = tid & 63, wave = tid >> 6;
  int mq = lane & 15, quad = lane >> 4;
  int wm = wave * 32;

#pragma unroll
  for (int u = 0; u < 8; ++u) {
    int unit = u * 256 + tid;
    int r = unit >> 4, c8 = (unit & 15) * 8;
    *(half8*)&Ks[r][c8] = *(const half8*)(kh + (size_t)(j0 + r) * 512 + kvh * 128 + c8);
  }

  float colacc[8] = {};
  for (int ib = j0 / 128; ib < SEQ / 128; ++ib) {
    int i0 = ib * 128;
    __syncthreads();
#pragma unroll
    for (int u = 0; u < 8; ++u) {
      int unit = u * 256 + tid;
      int r = unit >> 4, c8 = (unit & 15) * 8;
      *(half8*)&Qs[r][c8] = *(const half8*)(qh + (size_t)(i0 + r) * 2048 + h * 128 + c8);
    }
    __syncthreads();

    f32x4 acc[2][8] = {};
#pragma unroll
    for (int ks = 0; ks < 4; ++ks) {
      half8 af[2], bf[8];
#pragma unroll
      for (int rt = 0; rt < 2; ++rt) af[rt] = *(const half8*)&Qs[wm + rt * 16 + mq][ks * 32 + quad * 8];
#pragma unroll
      for (int ct = 0; ct < 8; ++ct) bf[ct] = *(const half8*)&Ks[ct * 16 + mq][ks * 32 + quad * 8];
#pragma unroll
      for (int rt = 0; rt < 2; ++rt)
#pragma unroll
        for (int ct = 0; ct < 8; ++ct)
          acc[rt][ct] = __builtin_amdgcn_mfma_f32_16x16x32_f16(af[rt], bf[ct], acc[rt][ct], 0, 0, 0);
    }

#pragma unroll
    for (int rt = 0; rt < 2; ++rt) {
      int rbase = i0 + wm + rt * 16 + quad * 4;
      float rm[4], ri[4];
#pragma unroll
      for (int r = 0; r < 4; ++r) {
        rm[r] = rowm[h * SEQ + rbase + r];
        ri[r] = 1.f / rowl[h * SEQ + rbase + r];
      }
#pragma unroll
      for (int ct = 0; ct < 8; ++ct) {
        int j = j0 + ct * 16 + mq;
        float cp = 0.f;
#pragma unroll
        for (int r = 0; r < 4; ++r) {
          if (j <= rbase + r)
            cp += __expf(acc[rt][ct][r] * SCALE - rm[r]) * ri[r];
        }
        colacc[ct] += cp;
      }
    }
  }
#pragma unroll
  for (int ct = 0; ct < 8; ++ct) {
    float v = colacc[ct];
    v += __shfl_xor(v, 16, 64);
    v += __shfl_xor(v, 32, 64);
    colacc[ct] = v;
  }
  __syncthreads();
  if (quad == 0) {
#pragma unroll
    for (int ct = 0; ct < 8; ++ct) colred[wave][ct * 16 + mq] = colacc[ct];
  }
  __syncthreads();
  if (tid < 128)
    colsum[h * SEQ + j0 + tid] =
        colred[0][tid] + colred[1][tid] + colred[2][tid] + colred[3][tid];
}

// ---------- top-HEAVY per head ----------
__global__ __launch_bounds__(64) void topk_k(const float* __restrict__ colsum,
                                             int* __restrict__ hidx) {
  int h = blockIdx.x, t = threadIdx.x;
  __shared__ float vals[SEQ];
  for (int j = t; j < SEQ; j += 64) vals[j] = colsum[h * SEQ + j];
  __syncthreads();
  for (int it = 0; it < HEAVY; ++it) {
    float bv = -INFINITY; int bi = SEQ - 1;
    for (int j = t; j < SEQ; j += 64) {
      float v = vals[j];
      if (v > bv) { bv = v; bi = j; }
    }
    for (int off = 32; off > 0; off >>= 1) {
      float ov = __shfl_xor(bv, off, 64);
      int   oi = __shfl_xor(bi, off, 64);
      if (ov > bv || (ov == bv && oi < bi)) { bv = ov; bi = oi; }
    }
    bi = min(max(bi, 0), SEQ - 1);
    if (t == 0) hidx[h * HEAVY + it] = bi;
    __syncthreads();
    vals[bi] = -INFINITY;
    __syncthreads();
  }
}

// ---------- attn3: MFMA sparse flash attention over heavy ∪ recent ----------
__global__ __launch_bounds__(512) void attn3(
    const _Float16* __restrict__ qh, const _Float16* __restrict__ kh,
    const _Float16* __restrict__ vh, const int* __restrict__ hidx,
    _Float16* __restrict__ ctx)
{
  constexpr int TB = 64;
  int i0 = blockIdx.x * 128, h = blockIdx.y, kvh = h >> 2;
  __shared__ _Float16 QP[128][136];       // Q staging; reused as P
  __shared__ _Float16 KVu[9216];          // union: K[64][136] / VT[128][72]
  __shared__ int shx[HEAVY];
  int tid = threadIdx.x, lane = tid & 63, wave = tid >> 6;
  int mq = lane & 15, quad = lane >> 4;
  int wm = wave * 16;

  _Float16 (*Ks)[136] = (_Float16(*)[136])KVu;
  _Float16 (*Vs)[72]  = (_Float16(*)[72])KVu;

#pragma unroll
  for (int u = 0; u < 4; ++u) {
    int unit = u * 512 + tid;
    int r = unit >> 4, c8 = (unit & 15) * 8;
    *(half8*)&QP[r][c8] = *(const half8*)(qh + (size_t)(i0 + r) * 2048 + h * 128 + c8);
  }
  for (int e = tid; e < HEAVY; e += 512) shx[e] = hidx[h * HEAVY + e];
  __syncthreads();

  half8 aq[4];
#pragma unroll
  for (int ks = 0; ks < 4; ++ks) aq[ks] = *(const half8*)&QP[wm + mq][ks * 32 + quad * 8];

  float runm[4], runl[4];
#pragma unroll
  for (int r = 0; r < 4; ++r) { runm[r] = -INFINITY; runl[r] = 0.f; }
  f32x4 acc_o[8] = {};

  int tb_lo = max(0, i0 - RECENT) >> 6;
  int tb_hi = (i0 + 127) >> 6;
  int nband = tb_hi - tb_lo + 1;
  int nheavy = (i0 + 127 > RECENT) ? ((HEAVY + TB - 1) / TB) : 0;
  int ntiles = nband + nheavy;

  for (int tt = 0; tt < ntiles; ++tt) {
    bool isheavy = tt >= nband;
    int j0 = isheavy ? 0 : (tb_lo + tt) * TB;
    int e0 = isheavy ? (tt - nband) * TB : 0;

    // stage K tile (64 cols x 128 dims)
#pragma unroll
    for (int u = 0; u < 2; ++u) {
      int unit = u * 512 + tid;
      int c = unit >> 4, d8 = (unit & 15) * 8;
      int jabs;
      if (!isheavy) jabs = j0 + c;
      else { int e = e0 + c; jabs = (e < HEAVY) ? shx[e] : 0; }
      *(half8*)&Ks[c][d8] = *(const half8*)(kh + (size_t)jabs * 512 + kvh * 128 + d8);
    }
    int jreg[4];
#pragma unroll
    for (int ct = 0; ct < 4; ++ct) {
      int c = ct * 16 + mq;
      if (!isheavy) jreg[ct] = j0 + c;
      else { int e = e0 + c; jreg[ct] = (e < HEAVY) ? shx[e] : (1 << 28); }
    }
    __syncthreads();

    // S = Q K^T
    f32x4 s[4] = {};
#pragma unroll
    for (int ks = 0; ks < 4; ++ks) {
      half8 bf[4];
#pragma unroll
      for (int ct = 0; ct < 4; ++ct) bf[ct] = *(const half8*)&Ks[ct * 16 + mq][ks * 32 + quad * 8];
#pragma unroll
      for (int ct = 0; ct < 4; ++ct)
        s[ct] = __builtin_amdgcn_mfma_f32_16x16x32_f16(aq[ks], bf[ct], s[ct], 0, 0, 0);
    }

    // mask + online softmax
    float p[4][4];
#pragma unroll
    for (int r = 0; r < 4; ++r) {
      int i = i0 + wm + quad * 4 + r;
      float sv[4];
      float mx = -INFINITY;
#pragma unroll
      for (int ct = 0; ct < 4; ++ct) {
        int j = jreg[ct];
        bool ok = isheavy ? (j < i - RECENT) : (j >= i - RECENT && j <= i);
        float x = ok ? s[ct][r] * SCALE : -INFINITY;
        sv[ct] = x;
        mx = fmaxf(mx, x);
      }
      for (int off = 1; off < 16; off <<= 1) mx = fmaxf(mx, __shfl_xor(mx, off, 64));
      float nm = fmaxf(runm[r], mx);
      float sn = (nm == -INFINITY) ? 0.f : nm;
      float alpha = (runm[r] == -INFINITY) ? 0.f : __expf(runm[r] - nm);
      float ps = 0.f;
#pragma unroll
      for (int ct = 0; ct < 4; ++ct) {
        float pe = (sv[ct] == -INFINITY) ? 0.f : __expf(sv[ct] - sn);
        p[ct][r] = pe;
        ps += pe;
      }
      for (int off = 1; off < 16; off <<= 1) ps += __shfl_xor(ps, off, 64);
      runl[r] = runl[r] * alpha + ps;
      runm[r] = nm;
#pragma unroll
      for (int ct = 0; ct < 8; ++ct) acc_o[ct][r] *= alpha;
    }
    __syncthreads();   // all waves done reading Ks

    // stage V^T (overwrites K region) and P (into QP)
#pragma unroll
    for (int u = 0; u < 2; ++u) {
      int unit = u * 512 + tid;
      int c = unit >> 4, d8 = (unit & 15) * 8;
      int jabs;
      if (!isheavy) jabs = j0 + c;
      else { int e = e0 + c; jabs = (e < HEAVY) ? shx[e] : 0; }
      half8 v8 = *(const half8*)(vh + (size_t)jabs * 512 + kvh * 128 + d8);
#pragma unroll
      for (int e2 = 0; e2 < 8; ++e2) Vs[d8 + e2][c] = v8[e2];
    }
#pragma unroll
    for (int ct = 0; ct < 4; ++ct)
#pragma unroll
      for (int r = 0; r < 4; ++r)
        QP[wm + quad * 4 + r][ct * 16 + mq] = (_Float16)p[ct][r];
    __syncthreads();

    // O += P V
#pragma unroll
    for (int ks = 0; ks < 2; ++ks) {
      half8 ap = *(const half8*)&QP[wm + mq][ks * 32 + quad * 8];
      half8 bf[8];
#pragma unroll
      for (int ct = 0; ct < 8; ++ct) bf[ct] = *(const half8*)&Vs[ct * 16 + mq][ks * 32 + quad * 8];
#pragma unroll
      for (int ct = 0; ct < 8; ++ct)
        acc_o[ct] = __builtin_amdgcn_mfma_f32_16x16x32_f16(ap, bf[ct], acc_o[ct], 0, 0, 0);
    }
    __syncthreads();   // done with Vs/QP before next tile staging
  }

  float inv[4];
#pragma unroll
  for (int r = 0; r < 4; ++r) inv[r] = (runl[r] > 0.f) ? 1.f / runl[r] : 0.f;
#pragma unroll
  for (int ct = 0; ct < 8; ++ct) {
    int d = ct * 16 + mq;
#pragma unroll
    for (int r = 0; r < 4; ++r) {
      int i = i0 + wm + quad * 4 + r;
      ctx[(size_t)i * 2048 + h * 128 + d] = (_Float16)(acc_o[ct][r] * inv[r]);
    }
  }
}

// ---------- launch ----------
extern "C" void kernel_launch(void* const* d_in, const int* in_sizes, int n_in,
                              void* d_out, int out_size, void* d_ws, size_t ws_size,
                              hipStream_t stream) {
  const float* hs   = (const float*)d_in[0];
  const float* cosb = (const float*)d_in[1];
  const float* sinb = (const float*)d_in[2];
  const float* Wq = (const float*)d_in[4];
  const float* bq = (const float*)d_in[5];
  const float* Wk = (const float*)d_in[6];
  const float* bk = (const float*)d_in[7];
  const float* Wv = (const float*)d_in[8];
  const float* bv = (const float*)d_in[9];
  const float* Wo = (const float*)d_in[10];
  float* out = (float*)d_out;

  char* ws = (char*)d_ws;
  float* q    = (float*)ws;                               // 16 MB @0
  _Float16* WkT = (_Float16*)ws;                          // 2 MB (dead before q)
  _Float16* WvT = (_Float16*)(ws + (2u << 20));           // 2 MB (dead before q)
  float* kbuf = q + (size_t)SEQ * 2048;                   // 4 MB @16M
  float* vbuf = kbuf + (size_t)SEQ * 512;                 // 4 MB @20M
  float* rowm = vbuf + (size_t)SEQ * 512;                 // @24M
  float* rowl = rowm + NH * SEQ;
  float* colsum = rowl + NH * SEQ;
  int*   hidx   = (int*)(colsum + NH * SEQ);
  _Float16* hsH = (_Float16*)(ws + (25u << 20));          // 8 MB @25M
  _Float16* qh  = hsH;                                    // reuse after Q gemm
  _Float16* WoT = (_Float16*)(ws + (33u << 20));          // 8 MB @33M
  _Float16* WqT = (_Float16*)(ws + (41u << 20));          // 8 MB @41M
  _Float16* ctxH = WqT;                                   // reuse after Q gemm
  _Float16* kh  = (_Float16*)(ws + (49u << 20));          // 2 MB @49M
  _Float16* vh  = (_Float16*)(ws + (51u << 20));          // 2 MB @51M
  // total ~53 MB

  cvt_h<<<(SEQ * 2048 / 4 + 255) / 256, 256, 0, stream>>>(hs, hsH, SEQ * 2048);
  transpose_h<<<dim3(512 / 64, 2048 / 64), 256, 0, stream>>>(Wk, WkT, 2048, 512);
  transpose_h<<<dim3(512 / 64, 2048 / 64), 256, 0, stream>>>(Wv, WvT, 2048, 512);
  transpose_h<<<dim3(2048 / 64, 2048 / 64), 256, 0, stream>>>(Wo, WoT, 2048, 2048);
  transpose_h<<<dim3(2048 / 64, 2048 / 64), 256, 0, stream>>>(Wq, WqT, 2048, 2048);

  gemm_h<<<dim3(512 / 128, 2048 / 128), 256, 0, stream>>>(hsH, WkT, bk, kbuf, SEQ, 512, 2048);
  gemm_h<<<dim3(512 / 128, 2048 / 128), 256, 0, stream>>>(hsH, WvT, bv, vbuf, SEQ, 512, 2048);
  gemm_h<<<dim3(2048 / 128, 2048 / 128), 256, 0, stream>>>(hsH, WqT, bq, q, SEQ, 2048, 2048);

  rope_simple<<<(SEQ * 16 * 64 + 255) / 256, 256, 0, stream>>>(q,    cosb, sinb, 16, qh);
  rope_simple<<<(SEQ * 4 * 64 + 255) / 256, 256, 0, stream>>>(kbuf, cosb, sinb, 4,  kh);
  cvt_h<<<(SEQ * 512 / 4 + 255) / 256, 256, 0, stream>>>(vbuf, vh, SEQ * 512);

  flashstats<<<dim3(SEQ / 128, NH), 256, 0, stream>>>(qh, kh, rowm, rowl);
  flashcolsum<<<dim3(SEQ / 128, NH), 256, 0, stream>>>(qh, kh, rowm, rowl, colsum);
  topk_k<<<NH, 64, 0, stream>>>(colsum, hidx);
  attn3<<<dim3(SEQ / 128, NH), 512, 0, stream>>>(qh, kh, vh, hidx, ctxH);

  gemm_h<<<dim3(2048 / 128, 2048 / 128), 256, 0, stream>>>(ctxH, WoT, (const float*)nullptr,
                                                           out, SEQ, 2048, 2048);
}

// Round 9
// 556.515 us; speedup vs baseline: 28.1215x; 1.6234x over previous
//
#include <hip/hip_runtime.h>
#include <hip/hip_bf16.h>
#include <math.h>

constexpr int SEQ    = 2048;
constexpr int NH     = 16;
constexpr int HEAVY  = 204;   // int(0.1*2048)
constexpr int RECENT = 204;   // int(0.1*2048)
constexpr float SCALE = 0.08838834764831845f; // 128^-0.5

typedef _Float16 half8 __attribute__((ext_vector_type(8)));
typedef float f32x4 __attribute__((ext_vector_type(4)));

// ---------- f32 -> f16 convert ----------
__global__ void cvt_h(const float* __restrict__ src, _Float16* __restrict__ dst, int n) {
  int i = (blockIdx.x * 256 + threadIdx.x) * 4;
  if (i + 3 < n) {
    float4 v = *(const float4*)(src + i);
    dst[i] = (_Float16)v.x; dst[i+1] = (_Float16)v.y;
    dst[i+2] = (_Float16)v.z; dst[i+3] = (_Float16)v.w;
  } else {
    for (int u = i; u < n; ++u) dst[u] = (_Float16)src[u];
  }
}

// ---------- transpose + convert: W f32 [K][N] -> WT f16 [N][K] ----------
__global__ __launch_bounds__(256) void transpose_h(
    const float* __restrict__ W, _Float16* __restrict__ WT, int K, int N) {
  __shared__ float T[64][65];
  int c = threadIdx.x & 63, rq = threadIdx.x >> 6;
  int n0 = blockIdx.x * 64, k0 = blockIdx.y * 64;
#pragma unroll
  for (int u = 0; u < 16; ++u) {
    int r = rq * 16 + u;
    T[r][c] = W[(size_t)(k0 + r) * N + n0 + c];
  }
  __syncthreads();
#pragma unroll
  for (int u = 0; u < 16; ++u) {
    int r = rq * 16 + u;
    WT[(size_t)(n0 + r) * K + k0 + c] = (_Float16)T[c][r];
  }
}

// ---------- MFMA f16 GEMM: C[m][n] = sum_k A[m][k]*BT[n][k] + bias[n] ----------
__global__ __launch_bounds__(256) void gemm_h(
    const _Float16* __restrict__ A, const _Float16* __restrict__ BT,
    const float* __restrict__ bias, float* __restrict__ C,
    int M, int N, int K)
{
  __shared__ _Float16 As[128][40];
  __shared__ _Float16 Bs[128][40];
  int tid = threadIdx.x;
  int lane = tid & 63, wave = tid >> 6;
  int wm = (wave & 1) * 64, wn = (wave >> 1) * 64;
  int m0 = blockIdx.y * 128, n0 = blockIdx.x * 128;

  f32x4 acc[4][4] = {};

  int srow = tid >> 2;
  int scol = (tid & 3) * 8;
  int mq = lane & 15, quad = lane >> 4;

  for (int k0 = 0; k0 < K; k0 += 32) {
    *(half8*)&As[srow][scol]      = *(const half8*)(A  + (size_t)(m0 + srow) * K + k0 + scol);
    *(half8*)&As[srow + 64][scol] = *(const half8*)(A  + (size_t)(m0 + srow + 64) * K + k0 + scol);
    *(half8*)&Bs[srow][scol]      = *(const half8*)(BT + (size_t)(n0 + srow) * K + k0 + scol);
    *(half8*)&Bs[srow + 64][scol] = *(const half8*)(BT + (size_t)(n0 + srow + 64) * K + k0 + scol);
    __syncthreads();
    half8 af[4], bf[4];
#pragma unroll
    for (int t4 = 0; t4 < 4; ++t4) {
      af[t4] = *(const half8*)&As[wm + t4 * 16 + mq][quad * 8];
      bf[t4] = *(const half8*)&Bs[wn + t4 * 16 + mq][quad * 8];
    }
#pragma unroll
    for (int mt = 0; mt < 4; ++mt)
#pragma unroll
      for (int nt = 0; nt < 4; ++nt)
        acc[mt][nt] = __builtin_amdgcn_mfma_f32_16x16x32_f16(af[mt], bf[nt], acc[mt][nt], 0, 0, 0);
    __syncthreads();
  }

#pragma unroll
  for (int mt = 0; mt < 4; ++mt)
#pragma unroll
    for (int nt = 0; nt < 4; ++nt) {
      int n = n0 + wn + nt * 16 + mq;
      float bb = bias ? bias[n] : 0.f;
#pragma unroll
      for (int r = 0; r < 4; ++r) {
        int m = m0 + wm + mt * 16 + quad * 4 + r;
        C[(size_t)m * N + n] = acc[mt][nt][r] + bb;
      }
    }
}

// ---------- in-place RoPE + f16 emit ----------
__global__ void rope_simple(float* __restrict__ x, const float* __restrict__ cosb,
                            const float* __restrict__ sinb, int H,
                            _Float16* __restrict__ xh) {
  int idx = blockIdx.x * 256 + threadIdx.x;
  int total = SEQ * H * 64;
  if (idx >= total) return;
  int d = idx & 63;
  int rest = idx >> 6;
  int h = rest % H;
  int s = rest / H;
  size_t base = (size_t)s * (H * 128) + h * 128;
  float* p = x + base;
  _Float16* ph = xh + base;
  float x1 = p[d], x2 = p[d + 64];
  float c1 = cosb[(size_t)s * 128 + d];
  float c2 = cosb[(size_t)s * 128 + d + 64];
  float s1 = sinb[(size_t)s * 128 + d];
  float s2 = sinb[(size_t)s * 128 + d + 64];
  float o1 = x1 * c1 - x2 * s1;
  float o2 = x2 * c2 + x1 * s2;
  p[d] = o1; p[d + 64] = o2;
  ph[d] = (_Float16)o1; ph[d + 64] = (_Float16)o2;
}

// ---------- S1: MFMA flash row stats (m_i, l_i) over causal scores ----------
__global__ __launch_bounds__(256) void flashstats(
    const _Float16* __restrict__ qh, const _Float16* __restrict__ kh,
    float* __restrict__ rowm, float* __restrict__ rowl)
{
  int i0 = blockIdx.x * 128, h = blockIdx.y, kvh = h >> 2;
  __shared__ _Float16 Qs[128][136];
  __shared__ _Float16 Ks[128][136];
  int tid = threadIdx.x, lane = tid & 63, wave = tid >> 6;
  int mq = lane & 15, quad = lane >> 4;
  int wm = wave * 32;

#pragma unroll
  for (int u = 0; u < 8; ++u) {
    int unit = u * 256 + tid;
    int r = unit >> 4, c8 = (unit & 15) * 8;
    *(half8*)&Qs[r][c8] = *(const half8*)(qh + (size_t)(i0 + r) * 2048 + h * 128 + c8);
  }

  float runm[2][4], runl[2][4];
#pragma unroll
  for (int rt = 0; rt < 2; ++rt)
#pragma unroll
    for (int r = 0; r < 4; ++r) { runm[rt][r] = -INFINITY; runl[rt][r] = 0.f; }

  int nblk = i0 / 128 + 1;
  for (int jb = 0; jb < nblk; ++jb) {
    int j0 = jb * 128;
    __syncthreads();
#pragma unroll
    for (int u = 0; u < 8; ++u) {
      int unit = u * 256 + tid;
      int r = unit >> 4, c8 = (unit & 15) * 8;
      *(half8*)&Ks[r][c8] = *(const half8*)(kh + (size_t)(j0 + r) * 512 + kvh * 128 + c8);
    }
    __syncthreads();

    f32x4 acc[2][8] = {};
#pragma unroll
    for (int ks = 0; ks < 4; ++ks) {
      half8 af[2], bf[8];
#pragma unroll
      for (int rt = 0; rt < 2; ++rt) af[rt] = *(const half8*)&Qs[wm + rt * 16 + mq][ks * 32 + quad * 8];
#pragma unroll
      for (int ct = 0; ct < 8; ++ct) bf[ct] = *(const half8*)&Ks[ct * 16 + mq][ks * 32 + quad * 8];
#pragma unroll
      for (int rt = 0; rt < 2; ++rt)
#pragma unroll
        for (int ct = 0; ct < 8; ++ct)
          acc[rt][ct] = __builtin_amdgcn_mfma_f32_16x16x32_f16(af[rt], bf[ct], acc[rt][ct], 0, 0, 0);
    }

#pragma unroll
    for (int rt = 0; rt < 2; ++rt) {
      int rbase = i0 + wm + rt * 16 + quad * 4;
#pragma unroll
      for (int ct = 0; ct < 8; ++ct) {
        int j = j0 + ct * 16 + mq;
#pragma unroll
        for (int r = 0; r < 4; ++r) {
          float s = acc[rt][ct][r] * SCALE;
          if (j > rbase + r) s = -INFINITY;
          acc[rt][ct][r] = s;
        }
      }
#pragma unroll
      for (int r = 0; r < 4; ++r) {
        float v = acc[rt][0][r];
#pragma unroll
        for (int ct = 1; ct < 8; ++ct) v = fmaxf(v, acc[rt][ct][r]);
        for (int off = 1; off < 16; off <<= 1) v = fmaxf(v, __shfl_xor(v, off, 64));
        float nm = fmaxf(runm[rt][r], v);
        float alpha = (runm[rt][r] == -INFINITY) ? 0.f : __expf(runm[rt][r] - nm);
        float ps = 0.f;
#pragma unroll
        for (int ct = 0; ct < 8; ++ct) ps += __expf(acc[rt][ct][r] - nm);
        for (int off = 1; off < 16; off <<= 1) ps += __shfl_xor(ps, off, 64);
        runl[rt][r] = runl[rt][r] * alpha + ps;
        runm[rt][r] = nm;
      }
    }
  }
  if (mq == 0) {
#pragma unroll
    for (int rt = 0; rt < 2; ++rt)
#pragma unroll
      for (int r = 0; r < 4; ++r) {
        int i = i0 + wm + rt * 16 + quad * 4 + r;
        rowm[h * SEQ + i] = runm[rt][r];
        rowl[h * SEQ + i] = runl[rt][r];
      }
  }
}

// ---------- S2: MFMA colsum[h][j] = sum_i exp(s_ij - m_i)/l_i ----------
__global__ __launch_bounds__(256) void flashcolsum(
    const _Float16* __restrict__ qh, const _Float16* __restrict__ kh,
    const float* __restrict__ rowm, const float* __restrict__ rowl,
    float* __restrict__ colsum)
{
  int j0 = blockIdx.x * 128, h = blockIdx.y, kvh = h >> 2;
  __shared__ _Float16 Qs[128][136];
  __shared__ _Float16 Ks[128][136];
  __shared__ float colred[4][128];
  int tid = threadIdx.x, lane = tid & 63, wave = tid >> 6;
  int mq = lane & 15, quad = lane >> 4;
  int wm = wave * 32;

#pragma unroll
  for (int u = 0; u < 8; ++u) {
    int unit = u * 256 + tid;
    int r = unit >> 4, c8 = (unit & 15) * 8;
    *(half8*)&Ks[r][c8] = *(const half8*)(kh + (size_t)(j0 + r) * 512 + kvh * 128 + c8);
  }

  float colacc[8] = {};
  for (int ib = j0 / 128; ib < SEQ / 128; ++ib) {
    int i0 = ib * 128;
    __syncthreads();
#pragma unroll
    for (int u = 0; u < 8; ++u) {
      int unit = u * 256 + tid;
      int r = unit >> 4, c8 = (unit & 15) * 8;
      *(half8*)&Qs[r][c8] = *(const half8*)(qh + (size_t)(i0 + r) * 2048 + h * 128 + c8);
    }
    __syncthreads();

    f32x4 acc[2][8] = {};
#pragma unroll
    for (int ks = 0; ks < 4; ++ks) {
      half8 af[2], bf[8];
#pragma unroll
      for (int rt = 0; rt < 2; ++rt) af[rt] = *(const half8*)&Qs[wm + rt * 16 + mq][ks * 32 + quad * 8];
#pragma unroll
      for (int ct = 0; ct < 8; ++ct) bf[ct] = *(const half8*)&Ks[ct * 16 + mq][ks * 32 + quad * 8];
#pragma unroll
      for (int rt = 0; rt < 2; ++rt)
#pragma unroll
        for (int ct = 0; ct < 8; ++ct)
          acc[rt][ct] = __builtin_amdgcn_mfma_f32_16x16x32_f16(af[rt], bf[ct], acc[rt][ct], 0, 0, 0);
    }

#pragma unroll
    for (int rt = 0; rt < 2; ++rt) {
      int rbase = i0 + wm + rt * 16 + quad * 4;
      float rm[4], ri[4];
#pragma unroll
      for (int r = 0; r < 4; ++r) {
        rm[r] = rowm[h * SEQ + rbase + r];
        ri[r] = 1.f / rowl[h * SEQ + rbase + r];
      }
#pragma unroll
      for (int ct = 0; ct < 8; ++ct) {
        int j = j0 + ct * 16 + mq;
        float cp = 0.f;
#pragma unroll
        for (int r = 0; r < 4; ++r) {
          if (j <= rbase + r)
            cp += __expf(acc[rt][ct][r] * SCALE - rm[r]) * ri[r];
        }
        colacc[ct] += cp;
      }
    }
  }
#pragma unroll
  for (int ct = 0; ct < 8; ++ct) {
    float v = colacc[ct];
    v += __shfl_xor(v, 16, 64);
    v += __shfl_xor(v, 32, 64);
    colacc[ct] = v;
  }
  __syncthreads();
  if (quad == 0) {
#pragma unroll
    for (int ct = 0; ct < 8; ++ct) colred[wave][ct * 16 + mq] = colacc[ct];
  }
  __syncthreads();
  if (tid < 128)
    colsum[h * SEQ + j0 + tid] =
        colred[0][tid] + colred[1][tid] + colred[2][tid] + colred[3][tid];
}

// ---------- top-HEAVY per head via radix select (positive floats -> monotone bits) ----------
__global__ __launch_bounds__(256) void topk_radix(const float* __restrict__ colsum,
                                                  int* __restrict__ hidx) {
  int h = blockIdx.x, t = threadIdx.x;
  __shared__ unsigned vals[SEQ];      // 8 KB
  __shared__ int hist[256];
  __shared__ int scanbuf[256];
  __shared__ unsigned s_prefix;
  __shared__ int s_k;

  for (int j = t; j < SEQ; j += 256) vals[j] = __float_as_uint(colsum[h * SEQ + j]);

  unsigned prefix = 0, maskFixed = 0;
  int k = HEAVY;
  for (int pass = 0; pass < 4; ++pass) {
    int shift = 24 - pass * 8;
    hist[t] = 0;
    __syncthreads();
    for (int j = t; j < SEQ; j += 256) {
      unsigned v = vals[j];
      if ((v & maskFixed) == prefix) atomicAdd(&hist[(v >> shift) & 255], 1);
    }
    __syncthreads();
    if (t == 0) {
      int c = 0, d = 255;
      for (; d > 0; --d) {
        if (c + hist[d] >= k) break;
        c += hist[d];
      }
      s_k = k - c;
      s_prefix = prefix | ((unsigned)d << shift);
    }
    __syncthreads();
    prefix = s_prefix;
    k = s_k;
    maskFixed |= (0xFFu << shift);
    __syncthreads();
  }
  unsigned T = prefix;   // exact bits of the HEAVY-th largest value
  int tieNeed = k;       // lowest-index ties of value T to keep

  // ordered selection: thread t owns contiguous elements [t*8, t*8+8)
  int base = t * 8;
  int cG = 0, cT = 0;
#pragma unroll
  for (int u = 0; u < 8; ++u) {
    unsigned v = vals[base + u];
    if (v > T) cG++;
    else if (v == T) cT++;
  }
  // inclusive scan of cG
  scanbuf[t] = cG; __syncthreads();
  for (int off = 1; off < 256; off <<= 1) {
    int x = (t >= off) ? scanbuf[t - off] : 0;
    __syncthreads();
    scanbuf[t] += x;
    __syncthreads();
  }
  int exG = scanbuf[t] - cG;
  int totG = scanbuf[255];           // == HEAVY - tieNeed
  __syncthreads();
  // inclusive scan of cT
  scanbuf[t] = cT; __syncthreads();
  for (int off = 1; off < 256; off <<= 1) {
    int x = (t >= off) ? scanbuf[t - off] : 0;
    __syncthreads();
    scanbuf[t] += x;
    __syncthreads();
  }
  int exT = scanbuf[t] - cT;

  int slotG = exG;
  int slotT = totG + exT;
#pragma unroll
  for (int u = 0; u < 8; ++u) {
    unsigned v = vals[base + u];
    if (v > T) {
      hidx[h * HEAVY + slotG] = base + u;
      slotG++;
    } else if (v == T) {
      if (slotT < totG + tieNeed) hidx[h * HEAVY + slotT] = base + u;
      slotT++;
    }
  }
}

// ---------- attn3: MFMA sparse flash attention over heavy ∪ recent ----------
__global__ __launch_bounds__(512) void attn3(
    const _Float16* __restrict__ qh, const _Float16* __restrict__ kh,
    const _Float16* __restrict__ vh, const int* __restrict__ hidx,
    _Float16* __restrict__ ctx)
{
  constexpr int TB = 64;
  int i0 = blockIdx.x * 128, h = blockIdx.y, kvh = h >> 2;
  __shared__ _Float16 QP[128][136];       // Q staging; reused as P
  __shared__ _Float16 KVu[9216];          // union: K[64][136] / VT[128][72]
  __shared__ int shx[HEAVY];
  int tid = threadIdx.x, lane = tid & 63, wave = tid >> 6;
  int mq = lane & 15, quad = lane >> 4;
  int wm = wave * 16;

  _Float16 (*Ks)[136] = (_Float16(*)[136])KVu;
  _Float16 (*Vs)[72]  = (_Float16(*)[72])KVu;

#pragma unroll
  for (int u = 0; u < 4; ++u) {
    int unit = u * 512 + tid;
    int r = unit >> 4, c8 = (unit & 15) * 8;
    *(half8*)&QP[r][c8] = *(const half8*)(qh + (size_t)(i0 + r) * 2048 + h * 128 + c8);
  }
  for (int e = tid; e < HEAVY; e += 512) shx[e] = hidx[h * HEAVY + e];
  __syncthreads();

  half8 aq[4];
#pragma unroll
  for (int ks = 0; ks < 4; ++ks) aq[ks] = *(const half8*)&QP[wm + mq][ks * 32 + quad * 8];

  float runm[4], runl[4];
#pragma unroll
  for (int r = 0; r < 4; ++r) { runm[r] = -INFINITY; runl[r] = 0.f; }
  f32x4 acc_o[8] = {};

  int tb_lo = max(0, i0 - RECENT) >> 6;
  int tb_hi = (i0 + 127) >> 6;
  int nband = tb_hi - tb_lo + 1;
  int nheavy = (i0 + 127 > RECENT) ? ((HEAVY + TB - 1) / TB) : 0;
  int ntiles = nband + nheavy;

  for (int tt = 0; tt < ntiles; ++tt) {
    bool isheavy = tt >= nband;
    int j0 = isheavy ? 0 : (tb_lo + tt) * TB;
    int e0 = isheavy ? (tt - nband) * TB : 0;

    // stage K tile (64 cols x 128 dims)
#pragma unroll
    for (int u = 0; u < 2; ++u) {
      int unit = u * 512 + tid;
      int c = unit >> 4, d8 = (unit & 15) * 8;
      int jabs;
      if (!isheavy) jabs = j0 + c;
      else { int e = e0 + c; jabs = (e < HEAVY) ? shx[e] : 0; }
      *(half8*)&Ks[c][d8] = *(const half8*)(kh + (size_t)jabs * 512 + kvh * 128 + d8);
    }
    int jreg[4];
#pragma unroll
    for (int ct = 0; ct < 4; ++ct) {
      int c = ct * 16 + mq;
      if (!isheavy) jreg[ct] = j0 + c;
      else { int e = e0 + c; jreg[ct] = (e < HEAVY) ? shx[e] : (1 << 28); }
    }
    __syncthreads();

    // S = Q K^T
    f32x4 s[4] = {};
#pragma unroll
    for (int ks = 0; ks < 4; ++ks) {
      half8 bf[4];
#pragma unroll
      for (int ct = 0; ct < 4; ++ct) bf[ct] = *(const half8*)&Ks[ct * 16 + mq][ks * 32 + quad * 8];
#pragma unroll
      for (int ct = 0; ct < 4; ++ct)
        s[ct] = __builtin_amdgcn_mfma_f32_16x16x32_f16(aq[ks], bf[ct], s[ct], 0, 0, 0);
    }

    // mask + online softmax
    float p[4][4];
#pragma unroll
    for (int r = 0; r < 4; ++r) {
      int i = i0 + wm + quad * 4 + r;
      float sv[4];
      float mx = -INFINITY;
#pragma unroll
      for (int ct = 0; ct < 4; ++ct) {
        int j = jreg[ct];
        bool ok = isheavy ? (j < i - RECENT) : (j >= i - RECENT && j <= i);
        float x = ok ? s[ct][r] * SCALE : -INFINITY;
        sv[ct] = x;
        mx = fmaxf(mx, x);
      }
      for (int off = 1; off < 16; off <<= 1) mx = fmaxf(mx, __shfl_xor(mx, off, 64));
      float nm = fmaxf(runm[r], mx);
      float sn = (nm == -INFINITY) ? 0.f : nm;
      float alpha = (runm[r] == -INFINITY) ? 0.f : __expf(runm[r] - nm);
      float ps = 0.f;
#pragma unroll
      for (int ct = 0; ct < 4; ++ct) {
        float pe = (sv[ct] == -INFINITY) ? 0.f : __expf(sv[ct] - sn);
        p[ct][r] = pe;
        ps += pe;
      }
      for (int off = 1; off < 16; off <<= 1) ps += __shfl_xor(ps, off, 64);
      runl[r] = runl[r] * alpha + ps;
      runm[r] = nm;
#pragma unroll
      for (int ct = 0; ct < 8; ++ct) acc_o[ct][r] *= alpha;
    }
    __syncthreads();   // all waves done reading Ks

    // stage V^T (overwrites K region) and P (into QP)
#pragma unroll
    for (int u = 0; u < 2; ++u) {
      int unit = u * 512 + tid;
      int c = unit >> 4, d8 = (unit & 15) * 8;
      int jabs;
      if (!isheavy) jabs = j0 + c;
      else { int e = e0 + c; jabs = (e < HEAVY) ? shx[e] : 0; }
      half8 v8 = *(const half8*)(vh + (size_t)jabs * 512 + kvh * 128 + d8);
#pragma unroll
      for (int e2 = 0; e2 < 8; ++e2) Vs[d8 + e2][c] = v8[e2];
    }
#pragma unroll
    for (int ct = 0; ct < 4; ++ct)
#pragma unroll
      for (int r = 0; r < 4; ++r)
        QP[wm + quad * 4 + r][ct * 16 + mq] = (_Float16)p[ct][r];
    __syncthreads();

    // O += P V
#pragma unroll
    for (int ks = 0; ks < 2; ++ks) {
      half8 ap = *(const half8*)&QP[wm + mq][ks * 32 + quad * 8];
      half8 bf[8];
#pragma unroll
      for (int ct = 0; ct < 8; ++ct) bf[ct] = *(const half8*)&Vs[ct * 16 + mq][ks * 32 + quad * 8];
#pragma unroll
      for (int ct = 0; ct < 8; ++ct)
        acc_o[ct] = __builtin_amdgcn_mfma_f32_16x16x32_f16(ap, bf[ct], acc_o[ct], 0, 0, 0);
    }
    __syncthreads();   // done with Vs/QP before next tile staging
  }

  float inv[4];
#pragma unroll
  for (int r = 0; r < 4; ++r) inv[r] = (runl[r] > 0.f) ? 1.f / runl[r] : 0.f;
#pragma unroll
  for (int ct = 0; ct < 8; ++ct) {
    int d = ct * 16 + mq;
#pragma unroll
    for (int r = 0; r < 4; ++r) {
      int i = i0 + wm + quad * 4 + r;
      ctx[(size_t)i * 2048 + h * 128 + d] = (_Float16)(acc_o[ct][r] * inv[r]);
    }
  }
}

// ---------- launch ----------
extern "C" void kernel_launch(void* const* d_in, const int* in_sizes, int n_in,
                              void* d_out, int out_size, void* d_ws, size_t ws_size,
                              hipStream_t stream) {
  const float* hs   = (const float*)d_in[0];
  const float* cosb = (const float*)d_in[1];
  const float* sinb = (const float*)d_in[2];
  const float* Wq = (const float*)d_in[4];
  const float* bq = (const float*)d_in[5];
  const float* Wk = (const float*)d_in[6];
  const float* bk = (const float*)d_in[7];
  const float* Wv = (const float*)d_in[8];
  const float* bv = (const float*)d_in[9];
  const float* Wo = (const float*)d_in[10];
  float* out = (float*)d_out;

  char* ws = (char*)d_ws;
  float* q    = (float*)ws;                               // 16 MB @0
  _Float16* WkT = (_Float16*)ws;                          // 2 MB (dead before q)
  _Float16* WvT = (_Float16*)(ws + (2u << 20));           // 2 MB (dead before q)
  float* kbuf = q + (size_t)SEQ * 2048;                   // 4 MB @16M
  float* vbuf = kbuf + (size_t)SEQ * 512;                 // 4 MB @20M
  float* rowm = vbuf + (size_t)SEQ * 512;                 // @24M
  float* rowl = rowm + NH * SEQ;
  float* colsum = rowl + NH * SEQ;
  int*   hidx   = (int*)(colsum + NH * SEQ);
  _Float16* hsH = (_Float16*)(ws + (25u << 20));          // 8 MB @25M
  _Float16* qh  = hsH;                                    // reuse after Q gemm
  _Float16* WoT = (_Float16*)(ws + (33u << 20));          // 8 MB @33M
  _Float16* WqT = (_Float16*)(ws + (41u << 20));          // 8 MB @41M
  _Float16* ctxH = WqT;                                   // reuse after Q gemm
  _Float16* kh  = (_Float16*)(ws + (49u << 20));          // 2 MB @49M
  _Float16* vh  = (_Float16*)(ws + (51u << 20));          // 2 MB @51M
  // total ~53 MB

  cvt_h<<<(SEQ * 2048 / 4 + 255) / 256, 256, 0, stream>>>(hs, hsH, SEQ * 2048);
  transpose_h<<<dim3(512 / 64, 2048 / 64), 256, 0, stream>>>(Wk, WkT, 2048, 512);
  transpose_h<<<dim3(512 / 64, 2048 / 64), 256, 0, stream>>>(Wv, WvT, 2048, 512);
  transpose_h<<<dim3(2048 / 64, 2048 / 64), 256, 0, stream>>>(Wo, WoT, 2048, 2048);
  transpose_h<<<dim3(2048 / 64, 2048 / 64), 256, 0, stream>>>(Wq, WqT, 2048, 2048);

  gemm_h<<<dim3(512 / 128, 2048 / 128), 256, 0, stream>>>(hsH, WkT, bk, kbuf, SEQ, 512, 2048);
  gemm_h<<<dim3(512 / 128, 2048 / 128), 256, 0, stream>>>(hsH, WvT, bv, vbuf, SEQ, 512, 2048);
  gemm_h<<<dim3(2048 / 128, 2048 / 128), 256, 0, stream>>>(hsH, WqT, bq, q, SEQ, 2048, 2048);

  rope_simple<<<(SEQ * 16 * 64 + 255) / 256, 256, 0, stream>>>(q,    cosb, sinb, 16, qh);
  rope_simple<<<(SEQ * 4 * 64 + 255) / 256, 256, 0, stream>>>(kbuf, cosb, sinb, 4,  kh);
  cvt_h<<<(SEQ * 512 / 4 + 255) / 256, 256, 0, stream>>>(vbuf, vh, SEQ * 512);

  flashstats<<<dim3(SEQ / 128, NH), 256, 0, stream>>>(qh, kh, rowm, rowl);
  flashcolsum<<<dim3(SEQ / 128, NH), 256, 0, stream>>>(qh, kh, rowm, rowl, colsum);
  topk_radix<<<NH, 256, 0, stream>>>(colsum, hidx);
  attn3<<<dim3(SEQ / 128, NH), 512, 0, stream>>>(qh, kh, vh, hidx, ctxH);

  gemm_h<<<dim3(2048 / 128, 2048 / 128), 256, 0, stream>>>(ctxH, WoT, (const float*)nullptr,
                                                           out, SEQ, 2048, 2048);
}

// Round 10
// 454.158 us; speedup vs baseline: 34.4595x; 1.2254x over previous
//
#include <hip/hip_runtime.h>
#include <hip/hip_bf16.h>
#include <math.h>

constexpr int SEQ    = 2048;
constexpr int NH     = 16;
constexpr int HEAVY  = 204;   // int(0.1*2048)
constexpr int RECENT = 204;   // int(0.1*2048)
constexpr float SCALE = 0.08838834764831845f; // 128^-0.5

typedef _Float16 half8 __attribute__((ext_vector_type(8)));
typedef float f32x4 __attribute__((ext_vector_type(4)));

// ---------- f32 -> f16 convert ----------
__global__ void cvt_h(const float* __restrict__ src, _Float16* __restrict__ dst, int n) {
  int i = (blockIdx.x * 256 + threadIdx.x) * 4;
  if (i + 3 < n) {
    float4 v = *(const float4*)(src + i);
    dst[i] = (_Float16)v.x; dst[i+1] = (_Float16)v.y;
    dst[i+2] = (_Float16)v.z; dst[i+3] = (_Float16)v.w;
  } else {
    for (int u = i; u < n; ++u) dst[u] = (_Float16)src[u];
  }
}

// ---------- transpose + convert: W f32 [K][N] -> WT f16 [N][K] ----------
__global__ __launch_bounds__(256) void transpose_h(
    const float* __restrict__ W, _Float16* __restrict__ WT, int K, int N) {
  __shared__ float T[64][65];
  int c = threadIdx.x & 63, rq = threadIdx.x >> 6;
  int n0 = blockIdx.x * 64, k0 = blockIdx.y * 64;
#pragma unroll
  for (int u = 0; u < 16; ++u) {
    int r = rq * 16 + u;
    T[r][c] = W[(size_t)(k0 + r) * N + n0 + c];
  }
  __syncthreads();
#pragma unroll
  for (int u = 0; u < 16; ++u) {
    int r = rq * 16 + u;
    WT[(size_t)(n0 + r) * K + k0 + c] = (_Float16)T[c][r];
  }
}

// ---------- concat bias [bq|bk|bv] -> 3072 floats ----------
__global__ void concat_bias(const float* __restrict__ bq, const float* __restrict__ bk,
                            const float* __restrict__ bv, float* __restrict__ b) {
  int i = blockIdx.x * 256 + threadIdx.x;
  if (i < 2048) b[i] = bq[i];
  else if (i < 2560) b[i] = bk[i - 2048];
  else if (i < 3072) b[i] = bv[i - 2560];
}

// ---------- MFMA f16 GEMM: C[m][n] = sum_k A[m][k]*BT[n][k] + bias[n] ----------
__global__ __launch_bounds__(256) void gemm_h(
    const _Float16* __restrict__ A, const _Float16* __restrict__ BT,
    const float* __restrict__ bias, float* __restrict__ C,
    int M, int N, int K)
{
  __shared__ _Float16 As[128][40];
  __shared__ _Float16 Bs[128][40];
  int tid = threadIdx.x;
  int lane = tid & 63, wave = tid >> 6;
  int wm = (wave & 1) * 64, wn = (wave >> 1) * 64;
  int m0 = blockIdx.y * 128, n0 = blockIdx.x * 128;

  f32x4 acc[4][4] = {};

  int srow = tid >> 2;
  int scol = (tid & 3) * 8;
  int mq = lane & 15, quad = lane >> 4;

  for (int k0 = 0; k0 < K; k0 += 32) {
    *(half8*)&As[srow][scol]      = *(const half8*)(A  + (size_t)(m0 + srow) * K + k0 + scol);
    *(half8*)&As[srow + 64][scol] = *(const half8*)(A  + (size_t)(m0 + srow + 64) * K + k0 + scol);
    *(half8*)&Bs[srow][scol]      = *(const half8*)(BT + (size_t)(n0 + srow) * K + k0 + scol);
    *(half8*)&Bs[srow + 64][scol] = *(const half8*)(BT + (size_t)(n0 + srow + 64) * K + k0 + scol);
    __syncthreads();
    half8 af[4], bf[4];
#pragma unroll
    for (int t4 = 0; t4 < 4; ++t4) {
      af[t4] = *(const half8*)&As[wm + t4 * 16 + mq][quad * 8];
      bf[t4] = *(const half8*)&Bs[wn + t4 * 16 + mq][quad * 8];
    }
#pragma unroll
    for (int mt = 0; mt < 4; ++mt)
#pragma unroll
      for (int nt = 0; nt < 4; ++nt)
        acc[mt][nt] = __builtin_amdgcn_mfma_f32_16x16x32_f16(af[mt], bf[nt], acc[mt][nt], 0, 0, 0);
    __syncthreads();
  }

#pragma unroll
  for (int mt = 0; mt < 4; ++mt)
#pragma unroll
    for (int nt = 0; nt < 4; ++nt) {
      int n = n0 + wn + nt * 16 + mq;
      float bb = bias ? bias[n] : 0.f;
#pragma unroll
      for (int r = 0; r < 4; ++r) {
        int m = m0 + wm + mt * 16 + quad * 4 + r;
        C[(size_t)m * N + n] = acc[mt][nt][r] + bb;
      }
    }
}

// ---------- postproc: qkv f32 [s][3072] -> RoPE'd qh/kh + vh (all f16) ----------
__global__ void postproc(const float* __restrict__ qkv, const float* __restrict__ cosb,
                         const float* __restrict__ sinb, _Float16* __restrict__ qh,
                         _Float16* __restrict__ kh, _Float16* __restrict__ vh) {
  int idx = blockIdx.x * 256 + threadIdx.x;
  const int NQ = SEQ * 16 * 64, NK = SEQ * 4 * 64, NV = SEQ * 4 * 128;
  if (idx < NQ) {
    int d = idx & 63; int rest = idx >> 6; int h = rest & 15; int s = rest >> 4;
    const float* p = qkv + (size_t)s * 3072 + h * 128;
    float x1 = p[d], x2 = p[d + 64];
    float c1 = cosb[(size_t)s * 128 + d], c2 = cosb[(size_t)s * 128 + d + 64];
    float s1 = sinb[(size_t)s * 128 + d], s2 = sinb[(size_t)s * 128 + d + 64];
    qh[(size_t)s * 2048 + h * 128 + d]      = (_Float16)(x1 * c1 - x2 * s1);
    qh[(size_t)s * 2048 + h * 128 + d + 64] = (_Float16)(x2 * c2 + x1 * s2);
  } else if (idx < NQ + NK) {
    int r = idx - NQ;
    int d = r & 63; int rest = r >> 6; int h = rest & 3; int s = rest >> 2;
    const float* p = qkv + (size_t)s * 3072 + 2048 + h * 128;
    float x1 = p[d], x2 = p[d + 64];
    float c1 = cosb[(size_t)s * 128 + d], c2 = cosb[(size_t)s * 128 + d + 64];
    float s1 = sinb[(size_t)s * 128 + d], s2 = sinb[(size_t)s * 128 + d + 64];
    kh[(size_t)s * 512 + h * 128 + d]      = (_Float16)(x1 * c1 - x2 * s1);
    kh[(size_t)s * 512 + h * 128 + d + 64] = (_Float16)(x2 * c2 + x1 * s2);
  } else if (idx < NQ + NK + NV) {
    int r = idx - NQ - NK;
    int d = r & 127; int rest = r >> 7; int h = rest & 3; int s = rest >> 2;
    vh[(size_t)s * 512 + h * 128 + d] = (_Float16)qkv[(size_t)s * 3072 + 2560 + h * 128 + d];
  }
}

// ---------- S1: MFMA flash row stats (m_i, l_i) over causal scores ----------
__global__ __launch_bounds__(256) void flashstats(
    const _Float16* __restrict__ qh, const _Float16* __restrict__ kh,
    float* __restrict__ rowm, float* __restrict__ rowl)
{
  int i0 = blockIdx.x * 128, h = blockIdx.y, kvh = h >> 2;
  __shared__ _Float16 Qs[128][136];
  __shared__ _Float16 Ks[128][136];
  int tid = threadIdx.x, lane = tid & 63, wave = tid >> 6;
  int mq = lane & 15, quad = lane >> 4;
  int wm = wave * 32;

#pragma unroll
  for (int u = 0; u < 8; ++u) {
    int unit = u * 256 + tid;
    int r = unit >> 4, c8 = (unit & 15) * 8;
    *(half8*)&Qs[r][c8] = *(const half8*)(qh + (size_t)(i0 + r) * 2048 + h * 128 + c8);
  }

  float runm[2][4], runl[2][4];
#pragma unroll
  for (int rt = 0; rt < 2; ++rt)
#pragma unroll
    for (int r = 0; r < 4; ++r) { runm[rt][r] = -INFINITY; runl[rt][r] = 0.f; }

  int nblk = i0 / 128 + 1;
  for (int jb = 0; jb < nblk; ++jb) {
    int j0 = jb * 128;
    __syncthreads();
#pragma unroll
    for (int u = 0; u < 8; ++u) {
      int unit = u * 256 + tid;
      int r = unit >> 4, c8 = (unit & 15) * 8;
      *(half8*)&Ks[r][c8] = *(const half8*)(kh + (size_t)(j0 + r) * 512 + kvh * 128 + c8);
    }
    __syncthreads();

    f32x4 acc[2][8] = {};
#pragma unroll
    for (int ks = 0; ks < 4; ++ks) {
      half8 af[2], bf[8];
#pragma unroll
      for (int rt = 0; rt < 2; ++rt) af[rt] = *(const half8*)&Qs[wm + rt * 16 + mq][ks * 32 + quad * 8];
#pragma unroll
      for (int ct = 0; ct < 8; ++ct) bf[ct] = *(const half8*)&Ks[ct * 16 + mq][ks * 32 + quad * 8];
#pragma unroll
      for (int rt = 0; rt < 2; ++rt)
#pragma unroll
        for (int ct = 0; ct < 8; ++ct)
          acc[rt][ct] = __builtin_amdgcn_mfma_f32_16x16x32_f16(af[rt], bf[ct], acc[rt][ct], 0, 0, 0);
    }

#pragma unroll
    for (int rt = 0; rt < 2; ++rt) {
      int rbase = i0 + wm + rt * 16 + quad * 4;
#pragma unroll
      for (int ct = 0; ct < 8; ++ct) {
        int j = j0 + ct * 16 + mq;
#pragma unroll
        for (int r = 0; r < 4; ++r) {
          float s = acc[rt][ct][r] * SCALE;
          if (j > rbase + r) s = -INFINITY;
          acc[rt][ct][r] = s;
        }
      }
#pragma unroll
      for (int r = 0; r < 4; ++r) {
        float v = acc[rt][0][r];
#pragma unroll
        for (int ct = 1; ct < 8; ++ct) v = fmaxf(v, acc[rt][ct][r]);
        for (int off = 1; off < 16; off <<= 1) v = fmaxf(v, __shfl_xor(v, off, 64));
        float nm = fmaxf(runm[rt][r], v);
        float alpha = (runm[rt][r] == -INFINITY) ? 0.f : __expf(runm[rt][r] - nm);
        float ps = 0.f;
#pragma unroll
        for (int ct = 0; ct < 8; ++ct) ps += __expf(acc[rt][ct][r] - nm);
        for (int off = 1; off < 16; off <<= 1) ps += __shfl_xor(ps, off, 64);
        runl[rt][r] = runl[rt][r] * alpha + ps;
        runm[rt][r] = nm;
      }
    }
  }
  if (mq == 0) {
#pragma unroll
    for (int rt = 0; rt < 2; ++rt)
#pragma unroll
      for (int r = 0; r < 4; ++r) {
        int i = i0 + wm + rt * 16 + quad * 4 + r;
        rowm[h * SEQ + i] = runm[rt][r];
        rowl[h * SEQ + i] = runl[rt][r];
      }
  }
}

// ---------- S2: MFMA colsum[h][j] = sum_i exp(s_ij - m_i)/l_i ----------
__global__ __launch_bounds__(256) void flashcolsum(
    const _Float16* __restrict__ qh, const _Float16* __restrict__ kh,
    const float* __restrict__ rowm, const float* __restrict__ rowl,
    float* __restrict__ colsum)
{
  int j0 = blockIdx.x * 128, h = blockIdx.y, kvh = h >> 2;
  __shared__ _Float16 Qs[128][136];
  __shared__ _Float16 Ks[128][136];
  __shared__ float colred[4][128];
  int tid = threadIdx.x, lane = tid & 63, wave = tid >> 6;
  int mq = lane & 15, quad = lane >> 4;
  int wm = wave * 32;

#pragma unroll
  for (int u = 0; u < 8; ++u) {
    int unit = u * 256 + tid;
    int r = unit >> 4, c8 = (unit & 15) * 8;
    *(half8*)&Ks[r][c8] = *(const half8*)(kh + (size_t)(j0 + r) * 512 + kvh * 128 + c8);
  }

  float colacc[8] = {};
  for (int ib = j0 / 128; ib < SEQ / 128; ++ib) {
    int i0 = ib * 128;
    __syncthreads();
#pragma unroll
    for (int u = 0; u < 8; ++u) {
      int unit = u * 256 + tid;
      int r = unit >> 4, c8 = (unit & 15) * 8;
      *(half8*)&Qs[r][c8] = *(const half8*)(qh + (size_t)(i0 + r) * 2048 + h * 128 + c8);
    }
    __syncthreads();

    f32x4 acc[2][8] = {};
#pragma unroll
    for (int ks = 0; ks < 4; ++ks) {
      half8 af[2], bf[8];
#pragma unroll
      for (int rt = 0; rt < 2; ++rt) af[rt] = *(const half8*)&Qs[wm + rt * 16 + mq][ks * 32 + quad * 8];
#pragma unroll
      for (int ct = 0; ct < 8; ++ct) bf[ct] = *(const half8*)&Ks[ct * 16 + mq][ks * 32 + quad * 8];
#pragma unroll
      for (int rt = 0; rt < 2; ++rt)
#pragma unroll
        for (int ct = 0; ct < 8; ++ct)
          acc[rt][ct] = __builtin_amdgcn_mfma_f32_16x16x32_f16(af[rt], bf[ct], acc[rt][ct], 0, 0, 0);
    }

#pragma unroll
    for (int rt = 0; rt < 2; ++rt) {
      int rbase = i0 + wm + rt * 16 + quad * 4;
      float rm[4], ri[4];
#pragma unroll
      for (int r = 0; r < 4; ++r) {
        rm[r] = rowm[h * SEQ + rbase + r];
        ri[r] = 1.f / rowl[h * SEQ + rbase + r];
      }
#pragma unroll
      for (int ct = 0; ct < 8; ++ct) {
        int j = j0 + ct * 16 + mq;
        float cp = 0.f;
#pragma unroll
        for (int r = 0; r < 4; ++r) {
          if (j <= rbase + r)
            cp += __expf(acc[rt][ct][r] * SCALE - rm[r]) * ri[r];
        }
        colacc[ct] += cp;
      }
    }
  }
#pragma unroll
  for (int ct = 0; ct < 8; ++ct) {
    float v = colacc[ct];
    v += __shfl_xor(v, 16, 64);
    v += __shfl_xor(v, 32, 64);
    colacc[ct] = v;
  }
  __syncthreads();
  if (quad == 0) {
#pragma unroll
    for (int ct = 0; ct < 8; ++ct) colred[wave][ct * 16 + mq] = colacc[ct];
  }
  __syncthreads();
  if (tid < 128)
    colsum[h * SEQ + j0 + tid] =
        colred[0][tid] + colred[1][tid] + colred[2][tid] + colred[3][tid];
}

// ---------- top-HEAVY per head via radix select ----------
__global__ __launch_bounds__(256) void topk_radix(const float* __restrict__ colsum,
                                                  int* __restrict__ hidx) {
  int h = blockIdx.x, t = threadIdx.x;
  __shared__ unsigned vals[SEQ];
  __shared__ int hist[256];
  __shared__ int scanbuf[256];
  __shared__ unsigned s_prefix;
  __shared__ int s_k;

  for (int j = t; j < SEQ; j += 256) vals[j] = __float_as_uint(colsum[h * SEQ + j]);

  unsigned prefix = 0, maskFixed = 0;
  int k = HEAVY;
  for (int pass = 0; pass < 4; ++pass) {
    int shift = 24 - pass * 8;
    hist[t] = 0;
    __syncthreads();
    for (int j = t; j < SEQ; j += 256) {
      unsigned v = vals[j];
      if ((v & maskFixed) == prefix) atomicAdd(&hist[(v >> shift) & 255], 1);
    }
    __syncthreads();
    if (t == 0) {
      int c = 0, d = 255;
      for (; d > 0; --d) {
        if (c + hist[d] >= k) break;
        c += hist[d];
      }
      s_k = k - c;
      s_prefix = prefix | ((unsigned)d << shift);
    }
    __syncthreads();
    prefix = s_prefix;
    k = s_k;
    maskFixed |= (0xFFu << shift);
    __syncthreads();
  }
  unsigned T = prefix;
  int tieNeed = k;

  int base = t * 8;
  int cG = 0, cT = 0;
#pragma unroll
  for (int u = 0; u < 8; ++u) {
    unsigned v = vals[base + u];
    if (v > T) cG++;
    else if (v == T) cT++;
  }
  scanbuf[t] = cG; __syncthreads();
  for (int off = 1; off < 256; off <<= 1) {
    int x = (t >= off) ? scanbuf[t - off] : 0;
    __syncthreads();
    scanbuf[t] += x;
    __syncthreads();
  }
  int exG = scanbuf[t] - cG;
  int totG = scanbuf[255];
  __syncthreads();
  scanbuf[t] = cT; __syncthreads();
  for (int off = 1; off < 256; off <<= 1) {
    int x = (t >= off) ? scanbuf[t - off] : 0;
    __syncthreads();
    scanbuf[t] += x;
    __syncthreads();
  }
  int exT = scanbuf[t] - cT;

  int slotG = exG;
  int slotT = totG + exT;
#pragma unroll
  for (int u = 0; u < 8; ++u) {
    unsigned v = vals[base + u];
    if (v > T) {
      hidx[h * HEAVY + slotG] = base + u;
      slotG++;
    } else if (v == T) {
      if (slotT < totG + tieNeed) hidx[h * HEAVY + slotT] = base + u;
      slotT++;
    }
  }
}

// ---------- attn3: MFMA sparse flash attention over heavy ∪ recent ----------
__global__ __launch_bounds__(512) void attn3(
    const _Float16* __restrict__ qh, const _Float16* __restrict__ kh,
    const _Float16* __restrict__ vh, const int* __restrict__ hidx,
    _Float16* __restrict__ ctx)
{
  constexpr int TB = 64;
  int i0 = blockIdx.x * 128, h = blockIdx.y, kvh = h >> 2;
  __shared__ _Float16 QP[128][136];       // Q staging; reused as P
  __shared__ _Float16 KVu[9216];          // union: K[64][136] / VT[128][72]
  __shared__ int shx[HEAVY];
  int tid = threadIdx.x, lane = tid & 63, wave = tid >> 6;
  int mq = lane & 15, quad = lane >> 4;
  int wm = wave * 16;

  _Float16 (*Ks)[136] = (_Float16(*)[136])KVu;
  _Float16 (*Vs)[72]  = (_Float16(*)[72])KVu;

#pragma unroll
  for (int u = 0; u < 4; ++u) {
    int unit = u * 512 + tid;
    int r = unit >> 4, c8 = (unit & 15) * 8;
    *(half8*)&QP[r][c8] = *(const half8*)(qh + (size_t)(i0 + r) * 2048 + h * 128 + c8);
  }
  for (int e = tid; e < HEAVY; e += 512) shx[e] = hidx[h * HEAVY + e];
  __syncthreads();

  half8 aq[4];
#pragma unroll
  for (int ks = 0; ks < 4; ++ks) aq[ks] = *(const half8*)&QP[wm + mq][ks * 32 + quad * 8];

  float runm[4], runl[4];
#pragma unroll
  for (int r = 0; r < 4; ++r) { runm[r] = -INFINITY; runl[r] = 0.f; }
  f32x4 acc_o[8] = {};

  int tb_lo = max(0, i0 - RECENT) >> 6;
  int tb_hi = (i0 + 127) >> 6;
  int nband = tb_hi - tb_lo + 1;
  int nheavy = (i0 + 127 > RECENT) ? ((HEAVY + TB - 1) / TB) : 0;
  int ntiles = nband + nheavy;

  for (int tt = 0; tt < ntiles; ++tt) {
    bool isheavy = tt >= nband;
    int j0 = isheavy ? 0 : (tb_lo + tt) * TB;
    int e0 = isheavy ? (tt - nband) * TB : 0;

    // stage K tile (64 cols x 128 dims): lanes write 256B contiguous -> conflict-free
#pragma unroll
    for (int u = 0; u < 2; ++u) {
      int unit = u * 512 + tid;
      int c = unit >> 4, d8 = (unit & 15) * 8;
      int jabs;
      if (!isheavy) jabs = j0 + c;
      else { int e = e0 + c; jabs = (e < HEAVY) ? shx[e] : 0; }
      *(half8*)&Ks[c][d8] = *(const half8*)(kh + (size_t)jabs * 512 + kvh * 128 + d8);
    }
    int jreg[4];
#pragma unroll
    for (int ct = 0; ct < 4; ++ct) {
      int c = ct * 16 + mq;
      if (!isheavy) jreg[ct] = j0 + c;
      else { int e = e0 + c; jreg[ct] = (e < HEAVY) ? shx[e] : (1 << 28); }
    }
    __syncthreads();

    // S = Q K^T
    f32x4 s[4] = {};
#pragma unroll
    for (int ks = 0; ks < 4; ++ks) {
      half8 bf[4];
#pragma unroll
      for (int ct = 0; ct < 4; ++ct) bf[ct] = *(const half8*)&Ks[ct * 16 + mq][ks * 32 + quad * 8];
#pragma unroll
      for (int ct = 0; ct < 4; ++ct)
        s[ct] = __builtin_amdgcn_mfma_f32_16x16x32_f16(aq[ks], bf[ct], s[ct], 0, 0, 0);
    }

    // mask + online softmax
    float p[4][4];
#pragma unroll
    for (int r = 0; r < 4; ++r) {
      int i = i0 + wm + quad * 4 + r;
      float sv[4];
      float mx = -INFINITY;
#pragma unroll
      for (int ct = 0; ct < 4; ++ct) {
        int j = jreg[ct];
        bool ok = isheavy ? (j < i - RECENT) : (j >= i - RECENT && j <= i);
        float x = ok ? s[ct][r] * SCALE : -INFINITY;
        sv[ct] = x;
        mx = fmaxf(mx, x);
      }
      for (int off = 1; off < 16; off <<= 1) mx = fmaxf(mx, __shfl_xor(mx, off, 64));
      float nm = fmaxf(runm[r], mx);
      float sn = (nm == -INFINITY) ? 0.f : nm;
      float alpha = (runm[r] == -INFINITY) ? 0.f : __expf(runm[r] - nm);
      float ps = 0.f;
#pragma unroll
      for (int ct = 0; ct < 4; ++ct) {
        float pe = (sv[ct] == -INFINITY) ? 0.f : __expf(sv[ct] - sn);
        p[ct][r] = pe;
        ps += pe;
      }
      for (int off = 1; off < 16; off <<= 1) ps += __shfl_xor(ps, off, 64);
      runl[r] = runl[r] * alpha + ps;
      runm[r] = nm;
#pragma unroll
      for (int ct = 0; ct < 8; ++ct) acc_o[ct][r] *= alpha;
    }
    __syncthreads();   // all waves done reading Ks

    // stage V^T (overwrites K region): c = lane -> consecutive-column writes, conflict-free
#pragma unroll
    for (int u = 0; u < 2; ++u) {
      int unit = u * 512 + tid;
      int c = unit & 63;           // KV column (lane-consecutive)
      int d8 = (unit >> 6) * 8;    // dim octet
      int jabs;
      if (!isheavy) jabs = j0 + c;
      else { int e = e0 + c; jabs = (e < HEAVY) ? shx[e] : 0; }
      half8 v8 = *(const half8*)(vh + (size_t)jabs * 512 + kvh * 128 + d8);
#pragma unroll
      for (int e2 = 0; e2 < 8; ++e2) Vs[d8 + e2][c] = v8[e2];
    }
#pragma unroll
    for (int ct = 0; ct < 4; ++ct)
#pragma unroll
      for (int r = 0; r < 4; ++r)
        QP[wm + quad * 4 + r][ct * 16 + mq] = (_Float16)p[ct][r];
    __syncthreads();

    // O += P V
#pragma unroll
    for (int ks = 0; ks < 2; ++ks) {
      half8 ap = *(const half8*)&QP[wm + mq][ks * 32 + quad * 8];
      half8 bf[8];
#pragma unroll
      for (int ct = 0; ct < 8; ++ct) bf[ct] = *(const half8*)&Vs[ct * 16 + mq][ks * 32 + quad * 8];
#pragma unroll
      for (int ct = 0; ct < 8; ++ct)
        acc_o[ct] = __builtin_amdgcn_mfma_f32_16x16x32_f16(ap, bf[ct], acc_o[ct], 0, 0, 0);
    }
    __syncthreads();   // done with Vs/QP before next tile staging
  }

  float inv[4];
#pragma unroll
  for (int r = 0; r < 4; ++r) inv[r] = (runl[r] > 0.f) ? 1.f / runl[r] : 0.f;
#pragma unroll
  for (int ct = 0; ct < 8; ++ct) {
    int d = ct * 16 + mq;
#pragma unroll
    for (int r = 0; r < 4; ++r) {
      int i = i0 + wm + quad * 4 + r;
      ctx[(size_t)i * 2048 + h * 128 + d] = (_Float16)(acc_o[ct][r] * inv[r]);
    }
  }
}

// ---------- launch ----------
extern "C" void kernel_launch(void* const* d_in, const int* in_sizes, int n_in,
                              void* d_out, int out_size, void* d_ws, size_t ws_size,
                              hipStream_t stream) {
  const float* hs   = (const float*)d_in[0];
  const float* cosb = (const float*)d_in[1];
  const float* sinb = (const float*)d_in[2];
  const float* Wq = (const float*)d_in[4];
  const float* bq = (const float*)d_in[5];
  const float* Wk = (const float*)d_in[6];
  const float* bk = (const float*)d_in[7];
  const float* Wv = (const float*)d_in[8];
  const float* bv = (const float*)d_in[9];
  const float* Wo = (const float*)d_in[10];
  float* out = (float*)d_out;

  char* ws = (char*)d_ws;
  // lifetimes:  WT(12M) -> [ctxH(8M) + rowm block];  qkv(24M) -> WoT(8M);  hsH(8M) -> kh+vh(4M)
  _Float16* WT   = (_Float16*)ws;                       // [3072][2048] f16 12 MB @0
  _Float16* ctxH = (_Float16*)ws;                       // 8 MB @0 (after WT dead)
  float* rowm    = (float*)(ws + (9u << 20));           // @9M (after WT dead)
  float* rowl    = rowm + NH * SEQ;
  float* colsum  = rowl + NH * SEQ;
  int*   hidx    = (int*)(colsum + NH * SEQ);
  float* qkv     = (float*)(ws + (12u << 20));          // [2048][3072] f32 24 MB @12M
  _Float16* WoT  = (_Float16*)(ws + (12u << 20));       // 8 MB @12M (after qkv dead)
  _Float16* hsH  = (_Float16*)(ws + (36u << 20));       // 8 MB @36M
  _Float16* kh   = (_Float16*)(ws + (36u << 20));       // 2 MB @36M (after hsH dead)
  _Float16* vh   = (_Float16*)(ws + (38u << 20));       // 2 MB @38M
  _Float16* qh   = (_Float16*)(ws + (44u << 20));       // 8 MB @44M
  float* biasqkv = (float*)(ws + (52u << 20));          // 12 KB @52M

  cvt_h<<<(SEQ * 2048 / 4 + 255) / 256, 256, 0, stream>>>(hs, hsH, SEQ * 2048);
  transpose_h<<<dim3(2048 / 64, 2048 / 64), 256, 0, stream>>>(Wq, WT, 2048, 2048);
  transpose_h<<<dim3(512 / 64, 2048 / 64), 256, 0, stream>>>(Wk, WT + (size_t)2048 * 2048, 2048, 512);
  transpose_h<<<dim3(512 / 64, 2048 / 64), 256, 0, stream>>>(Wv, WT + (size_t)2560 * 2048, 2048, 512);
  concat_bias<<<12, 256, 0, stream>>>(bq, bk, bv, biasqkv);

  // fused QKV projection: [2048][2048] x [3072][2048]^T -> qkv [2048][3072]
  gemm_h<<<dim3(3072 / 128, 2048 / 128), 256, 0, stream>>>(hsH, WT, biasqkv, qkv, SEQ, 3072, 2048);

  // RoPE + f16 emit (qh/kh/vh); qkv and hsH dead afterwards
  int np = SEQ * 16 * 64 + SEQ * 4 * 64 + SEQ * 4 * 128;
  postproc<<<(np + 255) / 256, 256, 0, stream>>>(qkv, cosb, sinb, qh, kh, vh);

  // Wo transpose into qkv's (now dead) space
  transpose_h<<<dim3(2048 / 64, 2048 / 64), 256, 0, stream>>>(Wo, WoT, 2048, 2048);

  flashstats<<<dim3(SEQ / 128, NH), 256, 0, stream>>>(qh, kh, rowm, rowl);
  flashcolsum<<<dim3(SEQ / 128, NH), 256, 0, stream>>>(qh, kh, rowm, rowl, colsum);
  topk_radix<<<NH, 256, 0, stream>>>(colsum, hidx);
  attn3<<<dim3(SEQ / 128, NH), 512, 0, stream>>>(qh, kh, vh, hidx, ctxH);

  gemm_h<<<dim3(2048 / 128, 2048 / 128), 256, 0, stream>>>(ctxH, WoT, (const float*)nullptr,
                                                           out, SEQ, 2048, 2048);
}